// Round 1
// baseline (1251.057 us; speedup 1.0000x reference)
//
#include <hip/hip_runtime.h>
#include <math.h>

// Problem dims
#define Bn 64
#define Sn 512
#define Hn 1024
#define En 10
#define Mn (Bn*Sn)          // 32768 rows of the attention GEMM
#define KIN 1035            // H + E + 1  (xin length)
#define KTOT 2059           // 1035 + 1024 (xin ++ h0)

// d_out flat offsets (floats): fin(64), h_new(65536), c_new(65536), attn_w(32768), sim(640)
#define OUT_FIN 0
#define OUT_H   64
#define OUT_C   65600
#define OUT_AW  131136
#define OUT_SIM 163904

// d_ws offsets (floats)
#define WS_DECP 0                      // 64*1024           = 65536
#define WS_PART 65536                  // 8 * 32768         = 262144 (score partials per N-slice)
#define WS_CTX  327680                 // 64*1024           = 65536
#define WS_XINT 393216                 // 2059*64           = 131776
// wts aliases WS_DECP (dec_proj dead after k2)            -> total ~2.1 MB

// ---------------------------------------------------------------------------
// k0: h0 [B,H] -> xinT rows 1035..2058 (K-major, lane index = b)
__global__ __launch_bounds__(256) void k0_h0T(const float* __restrict__ h0,
                                              float* __restrict__ xinT) {
    int idx = blockIdx.x * 256 + threadIdx.x;   // 65536 total
    int b = idx >> 10;
    int h = idx & 1023;
    xinT[(1035 + h) * 64 + b] = h0[idx];
}

// ---------------------------------------------------------------------------
// k1: dec_proj[b,g] = sum_h h0[b,h] * W_dec[g,h]   (wave per g, lane = b)
__global__ __launch_bounds__(256) void k1_decproj(const float* __restrict__ xinT,
                                                  const float* __restrict__ Wdec,
                                                  float* __restrict__ decp) {
    int g = blockIdx.x * 4 + (threadIdx.x >> 6);   // 1024 waves total
    int b = threadIdx.x & 63;
    const float* w = Wdec + (size_t)g * 1024;
    float a0 = 0.f, a1 = 0.f, a2 = 0.f, a3 = 0.f;
    for (int k = 0; k < 1024; k += 4) {
        a0 += xinT[(1035 + k + 0) * 64 + b] * w[k + 0];
        a1 += xinT[(1035 + k + 1) * 64 + b] * w[k + 1];
        a2 += xinT[(1035 + k + 2) * 64 + b] * w[k + 2];
        a3 += xinT[(1035 + k + 3) * 64 + b] * w[k + 3];
    }
    decp[b * 1024 + g] = (a0 + a1) + (a2 + a3);
}

// ---------------------------------------------------------------------------
// k2: partial attn scores.
//   C[m,g] = enc[m,:] . Wenc[g,:]   (A·B^T GEMM, M=32768, N=1024, K=1024)
//   part[nb][m] += sum_{g in N-tile} tanh(C + dec_proj[b,g]) * w_val[g]
// 128x128 block tile, 8x8 per-thread register tile, KT=32.
__global__ __launch_bounds__(256) void k2_scores(const float* __restrict__ enc,
                                                 const float* __restrict__ Wenc,
                                                 const float* __restrict__ decp,
                                                 const float* __restrict__ wval,
                                                 float* __restrict__ part) {
    __shared__ float As[32][132];   // k-major, +4 pad keeps rows 16B-aligned
    __shared__ float Bs[32][132];

    const int m0 = blockIdx.x * 128;          // 256 M-tiles; 128 | 512 => b uniform per tile
    const int n0 = blockIdx.y * 128;          // 8 N-tiles
    const int b  = m0 >> 9;
    const int tid = threadIdx.x;
    const int tx = tid & 15;                  // col group
    const int ty = tid >> 4;                  // row group

    float acc[8][8];
#pragma unroll
    for (int i = 0; i < 8; ++i)
#pragma unroll
        for (int j = 0; j < 8; ++j) acc[i][j] = 0.f;

    for (int k0 = 0; k0 < 1024; k0 += 32) {
        __syncthreads();
#pragma unroll
        for (int it = 0; it < 4; ++it) {
            int f = tid + it * 256;           // 0..1023: 128 rows x 8 float4
            int m  = f >> 3;
            int kq = f & 7;
            float4 va = *reinterpret_cast<const float4*>(enc  + (size_t)(m0 + m) * 1024 + k0 + kq * 4);
            As[kq * 4 + 0][m] = va.x; As[kq * 4 + 1][m] = va.y;
            As[kq * 4 + 2][m] = va.z; As[kq * 4 + 3][m] = va.w;
            float4 vb = *reinterpret_cast<const float4*>(Wenc + (size_t)(n0 + m) * 1024 + k0 + kq * 4);
            Bs[kq * 4 + 0][m] = vb.x; Bs[kq * 4 + 1][m] = vb.y;
            Bs[kq * 4 + 2][m] = vb.z; Bs[kq * 4 + 3][m] = vb.w;
        }
        __syncthreads();
#pragma unroll
        for (int kk = 0; kk < 32; ++kk) {
            float4 a0 = *reinterpret_cast<const float4*>(&As[kk][ty * 4]);
            float4 a1 = *reinterpret_cast<const float4*>(&As[kk][64 + ty * 4]);
            float4 b0 = *reinterpret_cast<const float4*>(&Bs[kk][tx * 4]);
            float4 b1 = *reinterpret_cast<const float4*>(&Bs[kk][64 + tx * 4]);
            float av[8] = {a0.x, a0.y, a0.z, a0.w, a1.x, a1.y, a1.z, a1.w};
            float bv[8] = {b0.x, b0.y, b0.z, b0.w, b1.x, b1.y, b1.z, b1.w};
#pragma unroll
            for (int i = 0; i < 8; ++i)
#pragma unroll
                for (int j = 0; j < 8; ++j) acc[i][j] += av[i] * bv[j];
        }
    }

    // epilogue: tanh(acc + dec_proj) . w_val, reduced over this block's 128 g's
    float wv[8], dp[8];
#pragma unroll
    for (int j = 0; j < 8; ++j) {
        int c = (j < 4) ? tx * 4 + j : 64 + tx * 4 + (j - 4);
        wv[j] = wval[n0 + c];
        dp[j] = decp[b * 1024 + n0 + c];
    }
#pragma unroll
    for (int i = 0; i < 8; ++i) {
        float p = 0.f;
#pragma unroll
        for (int j = 0; j < 8; ++j) p += tanhf(acc[i][j] + dp[j]) * wv[j];
        p += __shfl_xor(p, 1);
        p += __shfl_xor(p, 2);
        p += __shfl_xor(p, 4);
        p += __shfl_xor(p, 8);                // reduce across the 16 tx lanes
        if (tx == 0) {
            int r = (i < 4) ? ty * 4 + i : 64 + ty * 4 + (i - 4);
            part[(size_t)blockIdx.y * Mn + m0 + r] = p;
        }
    }
}

// ---------------------------------------------------------------------------
__device__ __forceinline__ float block_sum256(float v, float* red, int tid) {
#pragma unroll
    for (int off = 1; off < 64; off <<= 1) v += __shfl_xor(v, off);
    if ((tid & 63) == 0) red[tid >> 6] = v;
    __syncthreads();
    v = red[0] + red[1] + red[2] + red[3];
    __syncthreads();
    return v;
}

// k3a: sum 8 partial slices -> softmax over S -> attn_weight (out + ws)
__global__ __launch_bounds__(256) void k3a_softmax(const float* __restrict__ part,
                                                   float* __restrict__ wts,
                                                   float* __restrict__ out) {
    int b = blockIdx.x;
    int tid = threadIdx.x;
    __shared__ float red[8];
    int s0 = tid, s1 = tid + 256;
    float v0 = 0.f, v1 = 0.f;
#pragma unroll
    for (int nb = 0; nb < 8; ++nb) {
        v0 += part[(size_t)nb * Mn + b * 512 + s0];
        v1 += part[(size_t)nb * Mn + b * 512 + s1];
    }
    float mx = fmaxf(v0, v1);
#pragma unroll
    for (int off = 1; off < 64; off <<= 1) mx = fmaxf(mx, __shfl_xor(mx, off));
    if ((tid & 63) == 0) red[tid >> 6] = mx;
    __syncthreads();
    mx = fmaxf(fmaxf(red[0], red[1]), fmaxf(red[2], red[3]));
    __syncthreads();
    float e0 = __expf(v0 - mx), e1 = __expf(v1 - mx);
    float sm = block_sum256(e0 + e1, red, tid);
    float inv = 1.0f / sm;
    float w0 = e0 * inv, w1 = e1 * inv;
    wts[b * 512 + s0] = w0;
    wts[b * 512 + s1] = w1;
    out[OUT_AW + b * 512 + s0] = w0;
    out[OUT_AW + b * 512 + s1] = w1;
}

// k3b: context[b,h] = sum_s w[b,s] * enc[b,s,h]; also write context^T into xinT
__global__ __launch_bounds__(256) void k3b_context(const float* __restrict__ enc,
                                                   const float* __restrict__ wts,
                                                   float* __restrict__ ctx,
                                                   float* __restrict__ xinT) {
    int b = blockIdx.y;
    int h = blockIdx.x * 256 + threadIdx.x;
    const float* e = enc + (size_t)b * Sn * Hn + h;
    const float* w = wts + b * 512;
    float a0 = 0.f, a1 = 0.f, a2 = 0.f, a3 = 0.f;
    for (int s = 0; s < 512; s += 4) {
        a0 += w[s + 0] * e[(size_t)(s + 0) * 1024];
        a1 += w[s + 1] * e[(size_t)(s + 1) * 1024];
        a2 += w[s + 2] * e[(size_t)(s + 2) * 1024];
        a3 += w[s + 3] * e[(size_t)(s + 3) * 1024];
    }
    float acc = (a0 + a1) + (a2 + a3);
    ctx[b * 1024 + h] = acc;
    xinT[h * 64 + b] = acc;       // rows 0..1023 of xinT
}

// k4: sim[b,e'] = sum_e W_gate[e',e] * (ctx[b,:] . events[e,:]); fill sim & x rows of xinT
__global__ __launch_bounds__(256) void k4_sim(const float* __restrict__ ctx,
                                              const float* __restrict__ events,
                                              const float* __restrict__ Wg,
                                              const float* __restrict__ x,
                                              float* __restrict__ out,
                                              float* __restrict__ xinT) {
    int b = blockIdx.x;
    int tid = threadIdx.x, wv = tid >> 6, lane = tid & 63;
    __shared__ float tmp[16];
    const float* c = ctx + b * 1024;
    for (int e = wv; e < 10; e += 4) {
        const float* ev = events + e * 1024;
        float a = 0.f;
#pragma unroll
        for (int kk = 0; kk < 1024; kk += 64) a += c[kk + lane] * ev[kk + lane];
#pragma unroll
        for (int off = 1; off < 64; off <<= 1) a += __shfl_xor(a, off);
        if (lane == 0) tmp[e] = a;
    }
    __syncthreads();
    if (tid < 10) {
        float s2 = 0.f;
#pragma unroll
        for (int e = 0; e < 10; ++e) s2 += Wg[tid * 10 + e] * tmp[e];
        out[OUT_SIM + b * 10 + tid] = s2;
        xinT[(1024 + tid) * 64 + b] = s2;     // sim rows
    }
    if (tid == 10) xinT[1034 * 64 + b] = x[b]; // x row
}

// k5: single-step LSTM. Wave per hidden unit u (computes all 4 gates), lane = b.
__global__ __launch_bounds__(256) void k5_lstm(const float* __restrict__ xinT,
                                               const float* __restrict__ Wih,
                                               const float* __restrict__ Whh,
                                               const float* __restrict__ bih,
                                               const float* __restrict__ bhh,
                                               const float* __restrict__ c0,
                                               float* __restrict__ out) {
    int u = blockIdx.x * 4 + (threadIdx.x >> 6);   // 1024 waves
    int b = threadIdx.x & 63;
    const float* w0 = Wih + (size_t)(0 * 1024 + u) * KIN;
    const float* w1 = Wih + (size_t)(1 * 1024 + u) * KIN;
    const float* w2 = Wih + (size_t)(2 * 1024 + u) * KIN;
    const float* w3 = Wih + (size_t)(3 * 1024 + u) * KIN;
    float a0 = 0.f, a1 = 0.f, a2 = 0.f, a3 = 0.f;
#pragma unroll 4
    for (int k = 0; k < KIN; ++k) {
        float xv = xinT[k * 64 + b];
        a0 += xv * w0[k]; a1 += xv * w1[k]; a2 += xv * w2[k]; a3 += xv * w3[k];
    }
    const float* v0 = Whh + (size_t)(0 * 1024 + u) * 1024;
    const float* v1 = Whh + (size_t)(1 * 1024 + u) * 1024;
    const float* v2 = Whh + (size_t)(2 * 1024 + u) * 1024;
    const float* v3 = Whh + (size_t)(3 * 1024 + u) * 1024;
#pragma unroll 4
    for (int k = 0; k < 1024; ++k) {
        float xv = xinT[(1035 + k) * 64 + b];
        a0 += xv * v0[k]; a1 += xv * v1[k]; a2 += xv * v2[k]; a3 += xv * v3[k];
    }
    float gi = a0 + bih[u]        + bhh[u];
    float gf = a1 + bih[1024 + u] + bhh[1024 + u];
    float gg = a2 + bih[2048 + u] + bhh[2048 + u];
    float go = a3 + bih[3072 + u] + bhh[3072 + u];
    float cp = c0[b * 1024 + u];
    float si = 1.f / (1.f + __expf(-gi));
    float sf = 1.f / (1.f + __expf(-gf));
    float so = 1.f / (1.f + __expf(-go));
    float cn = sf * cp + si * tanhf(gg);
    float hn = so * tanhf(cn);
    out[OUT_H + b * 1024 + u] = hn;
    out[OUT_C + b * 1024 + u] = cn;
}

// k6: LayerNorm(h_new) -> y ; fin[b] = y . W_fin + b_fin
__global__ __launch_bounds__(256) void k6_lnfin(const float* __restrict__ lng,
                                                const float* __restrict__ lnb,
                                                const float* __restrict__ Wfin,
                                                const float* __restrict__ bfin,
                                                float* __restrict__ out) {
    int b = blockIdx.x, tid = threadIdx.x;
    __shared__ float red[8];
    const float* h = out + OUT_H + b * 1024;
    float v0 = h[tid], v1 = h[tid + 256], v2 = h[tid + 512], v3 = h[tid + 768];
    float mu = block_sum256(v0 + v1 + v2 + v3, red, tid) * (1.f / 1024.f);
    float d0 = v0 - mu, d1 = v1 - mu, d2 = v2 - mu, d3 = v3 - mu;
    float var = block_sum256(d0 * d0 + d1 * d1 + d2 * d2 + d3 * d3, red, tid) * (1.f / 1024.f);
    float rstd = rsqrtf(var + 1e-5f);
    float acc = (d0 * rstd * lng[tid]       + lnb[tid])       * Wfin[tid]
              + (d1 * rstd * lng[tid + 256] + lnb[tid + 256]) * Wfin[tid + 256]
              + (d2 * rstd * lng[tid + 512] + lnb[tid + 512]) * Wfin[tid + 512]
              + (d3 * rstd * lng[tid + 768] + lnb[tid + 768]) * Wfin[tid + 768];
    acc = block_sum256(acc, red, tid);
    if (tid == 0) out[OUT_FIN + b] = acc + bfin[0];
}

// ---------------------------------------------------------------------------
extern "C" void kernel_launch(void* const* d_in, const int* in_sizes, int n_in,
                              void* d_out, int out_size, void* d_ws, size_t ws_size,
                              hipStream_t stream) {
    (void)in_sizes; (void)n_in; (void)out_size; (void)ws_size;
    const float* x    = (const float*)d_in[0];
    const float* h0   = (const float*)d_in[1];
    const float* c0   = (const float*)d_in[2];
    const float* enc  = (const float*)d_in[3];
    const float* Wenc = (const float*)d_in[4];
    const float* Wdec = (const float*)d_in[5];
    const float* wval = (const float*)d_in[6];
    const float* Wg   = (const float*)d_in[7];
    const float* ev   = (const float*)d_in[8];
    const float* Wih  = (const float*)d_in[9];
    const float* Whh  = (const float*)d_in[10];
    const float* bih  = (const float*)d_in[11];
    const float* bhh  = (const float*)d_in[12];
    const float* lng  = (const float*)d_in[13];
    const float* lnb  = (const float*)d_in[14];
    const float* Wfin = (const float*)d_in[15];
    const float* bfin = (const float*)d_in[16];

    float* out  = (float*)d_out;
    float* ws   = (float*)d_ws;
    float* decp = ws + WS_DECP;
    float* part = ws + WS_PART;
    float* ctx  = ws + WS_CTX;
    float* xinT = ws + WS_XINT;
    float* wts  = ws + WS_DECP;   // alias: dec_proj is dead after k2

    k0_h0T    <<<256, 256, 0, stream>>>(h0, xinT);
    k1_decproj<<<256, 256, 0, stream>>>(xinT, Wdec, decp);
    k2_scores <<<dim3(256, 8), 256, 0, stream>>>(enc, Wenc, decp, wval, part);
    k3a_softmax<<<64, 256, 0, stream>>>(part, wts, out);
    k3b_context<<<dim3(4, 64), 256, 0, stream>>>(enc, wts, ctx, xinT);
    k4_sim    <<<64, 256, 0, stream>>>(ctx, ev, Wg, x, out, xinT);
    k5_lstm   <<<256, 256, 0, stream>>>(xinT, Wih, Whh, bih, bhh, c0, out);
    k6_lnfin  <<<64, 256, 0, stream>>>(lng, lnb, Wfin, bfin, out);
}

// Round 2
// 716.274 us; speedup vs baseline: 1.7466x; 1.7466x over previous
//
#include <hip/hip_runtime.h>
#include <math.h>

// Problem dims
#define Bn 64
#define Sn 512
#define Hn 1024
#define En 10
#define Mn (Bn*Sn)          // 32768 rows of the attention GEMM
#define KIN 1035            // H + E + 1  (xin length)

// d_out flat offsets (floats): fin(64), h_new(65536), c_new(65536), attn_w(32768), sim(640)
#define OUT_FIN 0
#define OUT_H   64
#define OUT_C   65600
#define OUT_AW  131136
#define OUT_SIM 163904

// d_ws offsets (floats)
#define WS_ENCB  0                     // 32M bf16 = 16777216 floats (64 MB)
#define WS_WENCB 16777216              // 1M bf16  = 524288 floats (2 MB)
#define WS_DECP  17301504              // 64*1024
#define WS_PART  17367040              // 8*32768
#define WS_CTX   17629184              // 64*1024
#define WS_XINT  17694720              // 2059*64
// total ~71.3 MB

typedef __attribute__((ext_vector_type(8))) short bf16x8;
typedef __attribute__((ext_vector_type(4))) float f32x4;

#define ASYNC_CP16(gptr, lptr) \
  __builtin_amdgcn_global_load_lds((const __attribute__((address_space(1))) void*)(gptr), \
                                   (__attribute__((address_space(3))) void*)(lptr), 16, 0, 0)

static __device__ __forceinline__ unsigned short f2bf(float f) {
    union { float f; unsigned int u; } v; v.f = f;
    unsigned int r = (v.u + 0x7fffu + ((v.u >> 16) & 1u)) >> 16;
    return (unsigned short)r;
}

// ---------------------------------------------------------------------------
// k_cast: enc fp32 -> bf16 (row-major), Wenc fp32 -> bf16. 8 elems/thread.
// blocks 0..16383 -> enc (33.5M elems); 16384..16895 -> Wenc (1M elems)
__global__ __launch_bounds__(256) void k_cast(const float* __restrict__ enc,
                                              const float* __restrict__ Wenc,
                                              unsigned short* __restrict__ encB,
                                              unsigned short* __restrict__ wencB) {
    const float* src; unsigned short* dst; size_t off;
    if (blockIdx.x < 16384) {
        src = enc; dst = encB;
        off = ((size_t)blockIdx.x * 256 + threadIdx.x) * 8;
    } else {
        src = Wenc; dst = wencB;
        off = ((size_t)(blockIdx.x - 16384) * 256 + threadIdx.x) * 8;
    }
    float4 v0 = *(const float4*)(src + off);
    float4 v1 = *(const float4*)(src + off + 4);
    ushort4 a; a.x = f2bf(v0.x); a.y = f2bf(v0.y); a.z = f2bf(v0.z); a.w = f2bf(v0.w);
    ushort4 b; b.x = f2bf(v1.x); b.y = f2bf(v1.y); b.z = f2bf(v1.z); b.w = f2bf(v1.w);
    *(ushort4*)(dst + off)     = a;
    *(ushort4*)(dst + off + 4) = b;
}

// ---------------------------------------------------------------------------
// k0: h0 [B,H] -> xinT rows 1035..2058 (K-major, lane index = b)
__global__ __launch_bounds__(256) void k0_h0T(const float* __restrict__ h0,
                                              float* __restrict__ xinT) {
    int idx = blockIdx.x * 256 + threadIdx.x;   // 65536 total
    int b = idx >> 10;
    int h = idx & 1023;
    xinT[(1035 + h) * 64 + b] = h0[idx];
}

// ---------------------------------------------------------------------------
// k1: dec_proj[b,g] = sum_h h0[b,h] * W_dec[g,h]   (wave per g, lane = b)
__global__ __launch_bounds__(256) void k1_decproj(const float* __restrict__ xinT,
                                                  const float* __restrict__ Wdec,
                                                  float* __restrict__ decp) {
    int g = blockIdx.x * 4 + (threadIdx.x >> 6);   // 1024 waves total
    int b = threadIdx.x & 63;
    const float* w = Wdec + (size_t)g * 1024;
    float a0 = 0.f, a1 = 0.f, a2 = 0.f, a3 = 0.f;
    for (int k = 0; k < 1024; k += 4) {
        a0 += xinT[(1035 + k + 0) * 64 + b] * w[k + 0];
        a1 += xinT[(1035 + k + 1) * 64 + b] * w[k + 1];
        a2 += xinT[(1035 + k + 2) * 64 + b] * w[k + 2];
        a3 += xinT[(1035 + k + 3) * 64 + b] * w[k + 3];
    }
    decp[b * 1024 + g] = (a0 + a1) + (a2 + a3);
}

// ---------------------------------------------------------------------------
// k2: bf16 MFMA attn-score GEMM + fused tanh.w_val epilogue.
//   C[m,g] = encB[m,:] . wencB[g,:]  (M=32768, N=1024, K=1024)
//   part[nb][m] = sum_{g in N-tile} tanh(C + dec_proj[b,g]) * w_val[g]
// 128x128 block tile, 4 waves 2x2, wave = 4x4 grid of 16x16x32 MFMA, BK=64.
// LDS layout: [k-quad (8)][row (128)][8 bf16] 16B chunks -> global_load_lds
// contiguity holds AND fragment ds_read_b128 is conflict-free.
__global__ __launch_bounds__(256) void k2_scores(const unsigned short* __restrict__ encB,
                                                 const unsigned short* __restrict__ wencB,
                                                 const float* __restrict__ decp,
                                                 const float* __restrict__ wval,
                                                 float* __restrict__ part) {
    __shared__ short As[8192];       // 8 quads * 128 rows * 8 bf16 = 16 KB
    __shared__ short Bs[8192];
    __shared__ float rsum[2][128];

    const int m0 = blockIdx.x * 128;          // 256 M-tiles (128 | 512 => b uniform)
    const int n0 = blockIdx.y * 128;          // 8 N-tiles
    const int b  = m0 >> 9;
    const int tid  = threadIdx.x;
    const int wave = tid >> 6;
    const int lane = tid & 63;
    const int wr = wave >> 1;                 // wave row (0/1): rows wr*64..+63
    const int wc = wave & 1;                  // wave col: cols wc*64..+63
    const int q4 = lane >> 4;                 // quad within wave
    const int ml = lane & 15;                 // m/n within 16-tile

    f32x4 acc[4][4];
#pragma unroll
    for (int i = 0; i < 4; ++i)
#pragma unroll
        for (int j = 0; j < 4; ++j) acc[i][j] = (f32x4){0.f, 0.f, 0.f, 0.f};

    const unsigned short* aTile = encB  + (size_t)m0 * 1024;
    const unsigned short* bTile = wencB + (size_t)n0 * 1024;

    for (int k0 = 0; k0 < 1024; k0 += 64) {
        __syncthreads();   // prior compute done reading LDS
#pragma unroll
        for (int t = 0; t < 4; ++t) {
            int cc = t * 4 + wave;            // 16 chunks: q=cc>>1, mb=(cc&1)*64
            int q  = cc >> 1;
            int mb = (cc & 1) << 6;
            ASYNC_CP16(aTile + (size_t)(mb + lane) * 1024 + k0 + q * 8,
                       &As[(q * 128 + mb) * 8]);
            ASYNC_CP16(bTile + (size_t)(mb + lane) * 1024 + k0 + q * 8,
                       &Bs[(q * 128 + mb) * 8]);
        }
        __syncthreads();   // drains vmcnt (global_load_lds) before use
#pragma unroll
        for (int s = 0; s < 2; ++s) {
            bf16x8 af[4], bfr[4];
#pragma unroll
            for (int i = 0; i < 4; ++i)
                af[i] = *(const bf16x8*)&As[((((s << 2) + q4) * 128) + wr * 64 + (i << 4) + ml) * 8];
#pragma unroll
            for (int j = 0; j < 4; ++j)
                bfr[j] = *(const bf16x8*)&Bs[((((s << 2) + q4) * 128) + wc * 64 + (j << 4) + ml) * 8];
#pragma unroll
            for (int i = 0; i < 4; ++i)
#pragma unroll
                for (int j = 0; j < 4; ++j)
                    acc[i][j] = __builtin_amdgcn_mfma_f32_16x16x32_bf16(af[i], bfr[j], acc[i][j], 0, 0, 0);
        }
    }

    // epilogue: row-sums of tanh(acc + dp) * wval over this block's 128 cols
    float dpv[4], wvv[4];
#pragma unroll
    for (int j = 0; j < 4; ++j) {
        int n = n0 + wc * 64 + (j << 4) + ml;
        dpv[j] = decp[b * 1024 + n];
        wvv[j] = wval[n];
    }
#pragma unroll
    for (int i = 0; i < 4; ++i) {
#pragma unroll
        for (int r = 0; r < 4; ++r) {
            float p = 0.f;
#pragma unroll
            for (int j = 0; j < 4; ++j) p += tanhf(acc[i][j][r] + dpv[j]) * wvv[j];
            p += __shfl_xor(p, 1);
            p += __shfl_xor(p, 2);
            p += __shfl_xor(p, 4);
            p += __shfl_xor(p, 8);     // reduce over the 16 cols held by this quad
            if (ml == 0) rsum[wc][wr * 64 + (i << 4) + q4 * 4 + r] = p;
        }
    }
    __syncthreads();
    if (tid < 128)
        part[(size_t)blockIdx.y * Mn + m0 + tid] = rsum[0][tid] + rsum[1][tid];
}

// ---------------------------------------------------------------------------
__device__ __forceinline__ float block_sum256(float v, float* red, int tid) {
#pragma unroll
    for (int off = 1; off < 64; off <<= 1) v += __shfl_xor(v, off);
    if ((tid & 63) == 0) red[tid >> 6] = v;
    __syncthreads();
    v = red[0] + red[1] + red[2] + red[3];
    __syncthreads();
    return v;
}

// k3a: sum 8 partial slices -> softmax over S -> attn_weight (out + ws)
__global__ __launch_bounds__(256) void k3a_softmax(const float* __restrict__ part,
                                                   float* __restrict__ wts,
                                                   float* __restrict__ out) {
    int b = blockIdx.x;
    int tid = threadIdx.x;
    __shared__ float red[8];
    int s0 = tid, s1 = tid + 256;
    float v0 = 0.f, v1 = 0.f;
#pragma unroll
    for (int nb = 0; nb < 8; ++nb) {
        v0 += part[(size_t)nb * Mn + b * 512 + s0];
        v1 += part[(size_t)nb * Mn + b * 512 + s1];
    }
    float mx = fmaxf(v0, v1);
#pragma unroll
    for (int off = 1; off < 64; off <<= 1) mx = fmaxf(mx, __shfl_xor(mx, off));
    if ((tid & 63) == 0) red[tid >> 6] = mx;
    __syncthreads();
    mx = fmaxf(fmaxf(red[0], red[1]), fmaxf(red[2], red[3]));
    __syncthreads();
    float e0 = __expf(v0 - mx), e1 = __expf(v1 - mx);
    float sm = block_sum256(e0 + e1, red, tid);
    float inv = 1.0f / sm;
    float w0 = e0 * inv, w1 = e1 * inv;
    wts[b * 512 + s0] = w0;
    wts[b * 512 + s1] = w1;
    out[OUT_AW + b * 512 + s0] = w0;
    out[OUT_AW + b * 512 + s1] = w1;
}

// k3b: context[b,h] = sum_s w[b,s] * enc[b,s,h]; also write context^T into xinT
__global__ __launch_bounds__(256) void k3b_context(const float* __restrict__ enc,
                                                   const float* __restrict__ wts,
                                                   float* __restrict__ ctx,
                                                   float* __restrict__ xinT) {
    int b = blockIdx.y;
    int h = blockIdx.x * 256 + threadIdx.x;
    const float* e = enc + (size_t)b * Sn * Hn + h;
    const float* w = wts + b * 512;
    float a0 = 0.f, a1 = 0.f, a2 = 0.f, a3 = 0.f;
    for (int s = 0; s < 512; s += 4) {
        a0 += w[s + 0] * e[(size_t)(s + 0) * 1024];
        a1 += w[s + 1] * e[(size_t)(s + 1) * 1024];
        a2 += w[s + 2] * e[(size_t)(s + 2) * 1024];
        a3 += w[s + 3] * e[(size_t)(s + 3) * 1024];
    }
    float acc = (a0 + a1) + (a2 + a3);
    ctx[b * 1024 + h] = acc;
    xinT[h * 64 + b] = acc;       // rows 0..1023 of xinT
}

// k4: sim[b,e'] = sum_e W_gate[e',e] * (ctx[b,:] . events[e,:]); fill sim & x rows of xinT
__global__ __launch_bounds__(256) void k4_sim(const float* __restrict__ ctx,
                                              const float* __restrict__ events,
                                              const float* __restrict__ Wg,
                                              const float* __restrict__ x,
                                              float* __restrict__ out,
                                              float* __restrict__ xinT) {
    int b = blockIdx.x;
    int tid = threadIdx.x, wv = tid >> 6, lane = tid & 63;
    __shared__ float tmp[16];
    const float* c = ctx + b * 1024;
    for (int e = wv; e < 10; e += 4) {
        const float* ev = events + e * 1024;
        float a = 0.f;
#pragma unroll
        for (int kk = 0; kk < 1024; kk += 64) a += c[kk + lane] * ev[kk + lane];
#pragma unroll
        for (int off = 1; off < 64; off <<= 1) a += __shfl_xor(a, off);
        if (lane == 0) tmp[e] = a;
    }
    __syncthreads();
    if (tid < 10) {
        float s2 = 0.f;
#pragma unroll
        for (int e = 0; e < 10; ++e) s2 += Wg[tid * 10 + e] * tmp[e];
        out[OUT_SIM + b * 10 + tid] = s2;
        xinT[(1024 + tid) * 64 + b] = s2;     // sim rows
    }
    if (tid == 10) xinT[1034 * 64 + b] = x[b]; // x row
}

// k5: single-step LSTM. Wave per hidden unit u (computes all 4 gates), lane = b.
__global__ __launch_bounds__(256) void k5_lstm(const float* __restrict__ xinT,
                                               const float* __restrict__ Wih,
                                               const float* __restrict__ Whh,
                                               const float* __restrict__ bih,
                                               const float* __restrict__ bhh,
                                               const float* __restrict__ c0,
                                               float* __restrict__ out) {
    int u = blockIdx.x * 4 + (threadIdx.x >> 6);   // 1024 waves
    int b = threadIdx.x & 63;
    const float* w0 = Wih + (size_t)(0 * 1024 + u) * KIN;
    const float* w1 = Wih + (size_t)(1 * 1024 + u) * KIN;
    const float* w2 = Wih + (size_t)(2 * 1024 + u) * KIN;
    const float* w3 = Wih + (size_t)(3 * 1024 + u) * KIN;
    float a0 = 0.f, a1 = 0.f, a2 = 0.f, a3 = 0.f;
#pragma unroll 4
    for (int k = 0; k < KIN; ++k) {
        float xv = xinT[k * 64 + b];
        a0 += xv * w0[k]; a1 += xv * w1[k]; a2 += xv * w2[k]; a3 += xv * w3[k];
    }
    const float* v0 = Whh + (size_t)(0 * 1024 + u) * 1024;
    const float* v1 = Whh + (size_t)(1 * 1024 + u) * 1024;
    const float* v2 = Whh + (size_t)(2 * 1024 + u) * 1024;
    const float* v3 = Whh + (size_t)(3 * 1024 + u) * 1024;
#pragma unroll 4
    for (int k = 0; k < 1024; ++k) {
        float xv = xinT[(1035 + k) * 64 + b];
        a0 += xv * v0[k]; a1 += xv * v1[k]; a2 += xv * v2[k]; a3 += xv * v3[k];
    }
    float gi = a0 + bih[u]        + bhh[u];
    float gf = a1 + bih[1024 + u] + bhh[1024 + u];
    float gg = a2 + bih[2048 + u] + bhh[2048 + u];
    float go = a3 + bih[3072 + u] + bhh[3072 + u];
    float cp = c0[b * 1024 + u];
    float si = 1.f / (1.f + __expf(-gi));
    float sf = 1.f / (1.f + __expf(-gf));
    float so = 1.f / (1.f + __expf(-go));
    float cn = sf * cp + si * tanhf(gg);
    float hn = so * tanhf(cn);
    out[OUT_H + b * 1024 + u] = hn;
    out[OUT_C + b * 1024 + u] = cn;
}

// k6: LayerNorm(h_new) -> y ; fin[b] = y . W_fin + b_fin
__global__ __launch_bounds__(256) void k6_lnfin(const float* __restrict__ lng,
                                                const float* __restrict__ lnb,
                                                const float* __restrict__ Wfin,
                                                const float* __restrict__ bfin,
                                                float* __restrict__ out) {
    int b = blockIdx.x, tid = threadIdx.x;
    __shared__ float red[8];
    const float* h = out + OUT_H + b * 1024;
    float v0 = h[tid], v1 = h[tid + 256], v2 = h[tid + 512], v3 = h[tid + 768];
    float mu = block_sum256(v0 + v1 + v2 + v3, red, tid) * (1.f / 1024.f);
    float d0 = v0 - mu, d1 = v1 - mu, d2 = v2 - mu, d3 = v3 - mu;
    float var = block_sum256(d0 * d0 + d1 * d1 + d2 * d2 + d3 * d3, red, tid) * (1.f / 1024.f);
    float rstd = rsqrtf(var + 1e-5f);
    float acc = (d0 * rstd * lng[tid]       + lnb[tid])       * Wfin[tid]
              + (d1 * rstd * lng[tid + 256] + lnb[tid + 256]) * Wfin[tid + 256]
              + (d2 * rstd * lng[tid + 512] + lnb[tid + 512]) * Wfin[tid + 512]
              + (d3 * rstd * lng[tid + 768] + lnb[tid + 768]) * Wfin[tid + 768];
    acc = block_sum256(acc, red, tid);
    if (tid == 0) out[OUT_FIN + b] = acc + bfin[0];
}

// ---------------------------------------------------------------------------
extern "C" void kernel_launch(void* const* d_in, const int* in_sizes, int n_in,
                              void* d_out, int out_size, void* d_ws, size_t ws_size,
                              hipStream_t stream) {
    (void)in_sizes; (void)n_in; (void)out_size; (void)ws_size;
    const float* x    = (const float*)d_in[0];
    const float* h0   = (const float*)d_in[1];
    const float* c0   = (const float*)d_in[2];
    const float* enc  = (const float*)d_in[3];
    const float* Wenc = (const float*)d_in[4];
    const float* Wdec = (const float*)d_in[5];
    const float* wval = (const float*)d_in[6];
    const float* Wg   = (const float*)d_in[7];
    const float* ev   = (const float*)d_in[8];
    const float* Wih  = (const float*)d_in[9];
    const float* Whh  = (const float*)d_in[10];
    const float* bih  = (const float*)d_in[11];
    const float* bhh  = (const float*)d_in[12];
    const float* lng  = (const float*)d_in[13];
    const float* lnb  = (const float*)d_in[14];
    const float* Wfin = (const float*)d_in[15];
    const float* bfin = (const float*)d_in[16];

    float* out  = (float*)d_out;
    float* ws   = (float*)d_ws;
    unsigned short* encB  = (unsigned short*)(ws + WS_ENCB);
    unsigned short* wencB = (unsigned short*)(ws + WS_WENCB);
    float* decp = ws + WS_DECP;
    float* part = ws + WS_PART;
    float* ctx  = ws + WS_CTX;
    float* xinT = ws + WS_XINT;
    float* wts  = ws + WS_DECP;   // alias: dec_proj is dead after k2

    k_cast    <<<16896, 256, 0, stream>>>(enc, Wenc, encB, wencB);
    k0_h0T    <<<256, 256, 0, stream>>>(h0, xinT);
    k1_decproj<<<256, 256, 0, stream>>>(xinT, Wdec, decp);
    k2_scores <<<dim3(256, 8), 256, 0, stream>>>(encB, wencB, decp, wval, part);
    k3a_softmax<<<64, 256, 0, stream>>>(part, wts, out);
    k3b_context<<<dim3(4, 64), 256, 0, stream>>>(enc, wts, ctx, xinT);
    k4_sim    <<<64, 256, 0, stream>>>(ctx, ev, Wg, x, out, xinT);
    k5_lstm   <<<256, 256, 0, stream>>>(xinT, Wih, Whh, bih, bhh, c0, out);
    k6_lnfin  <<<64, 256, 0, stream>>>(lng, lnb, Wfin, bfin, out);
}

// Round 3
// 523.680 us; speedup vs baseline: 2.3890x; 1.3678x over previous
//
#include <hip/hip_runtime.h>
#include <math.h>

// Problem dims
#define Bn 64
#define Sn 512
#define Hn 1024
#define En 10
#define Mn (Bn*Sn)          // 32768 rows of the attention GEMM
#define KIN 1035            // H + E + 1  (xin length)
#define KP  2112            // padded LSTM K: 2059 -> 33*64

// d_out flat offsets (floats): fin(64), h_new(65536), c_new(65536), attn_w(32768), sim(640)
#define OUT_FIN 0
#define OUT_H   64
#define OUT_C   65600
#define OUT_AW  131136
#define OUT_SIM 163904

// d_ws offsets (floats)
#define WS_ENCB  0                     // 32M bf16 = 16777216 floats (64 MB); dead after k3b
#define WS_WENCB 16777216              // 1M bf16  = 524288 floats
#define WS_DECP  17301504              // 64*1024
#define WS_PART  17367040              // 8*32768
#define WS_CTX   17629184              // 64*1024
#define WS_XINT  17694720              // 2059*64
// --- aliases inside the (dead after k3b) encB region ---
#define WS_WCATB 0                     // 4096*2112 bf16 = 4325376 floats
#define WS_GPART 4325376               // 8*64*4096 fp32 = 2097152 floats
#define WS_XINB  6422528               // 64*2112 bf16   = 67584 floats
// peak ws ~71.3 MB (unchanged from round 2)

typedef __attribute__((ext_vector_type(8))) short bf16x8;
typedef __attribute__((ext_vector_type(4))) float f32x4;

#define ASYNC_CP16(gptr, lptr) \
  __builtin_amdgcn_global_load_lds((const __attribute__((address_space(1))) void*)(gptr), \
                                   (__attribute__((address_space(3))) void*)(lptr), 16, 0, 0)

static __device__ __forceinline__ unsigned short f2bf(float f) {
    union { float f; unsigned int u; } v; v.f = f;
    unsigned int r = (v.u + 0x7fffu + ((v.u >> 16) & 1u)) >> 16;
    return (unsigned short)r;
}
static __device__ __forceinline__ float bf2f(unsigned short h) {
    union { unsigned int u; float f; } v; v.u = ((unsigned int)h) << 16;
    return v.f;
}

// ---------------------------------------------------------------------------
// k_cast: enc fp32 -> bf16 (row-major), Wenc fp32 -> bf16. 8 elems/thread.
__global__ __launch_bounds__(256) void k_cast(const float* __restrict__ enc,
                                              const float* __restrict__ Wenc,
                                              unsigned short* __restrict__ encB,
                                              unsigned short* __restrict__ wencB) {
    const float* src; unsigned short* dst; size_t off;
    if (blockIdx.x < 16384) {
        src = enc; dst = encB;
        off = ((size_t)blockIdx.x * 256 + threadIdx.x) * 8;
    } else {
        src = Wenc; dst = wencB;
        off = ((size_t)(blockIdx.x - 16384) * 256 + threadIdx.x) * 8;
    }
    float4 v0 = *(const float4*)(src + off);
    float4 v1 = *(const float4*)(src + off + 4);
    ushort4 a; a.x = f2bf(v0.x); a.y = f2bf(v0.y); a.z = f2bf(v0.z); a.w = f2bf(v0.w);
    ushort4 b; b.x = f2bf(v1.x); b.y = f2bf(v1.y); b.z = f2bf(v1.z); b.w = f2bf(v1.w);
    *(ushort4*)(dst + off)     = a;
    *(ushort4*)(dst + off + 4) = b;
}

// ---------------------------------------------------------------------------
// k0: h0 [B,H] -> xinT rows 1035..2058 (K-major, lane index = b) — feeds k1 only
__global__ __launch_bounds__(256) void k0_h0T(const float* __restrict__ h0,
                                              float* __restrict__ xinT) {
    int idx = blockIdx.x * 256 + threadIdx.x;   // 65536 total
    int b = idx >> 10;
    int h = idx & 1023;
    xinT[(1035 + h) * 64 + b] = h0[idx];
}

// ---------------------------------------------------------------------------
// k1: dec_proj[b,g] = sum_h h0[b,h] * W_dec[g,h]   (wave per g, lane = b)
__global__ __launch_bounds__(256) void k1_decproj(const float* __restrict__ xinT,
                                                  const float* __restrict__ Wdec,
                                                  float* __restrict__ decp) {
    int g = blockIdx.x * 4 + (threadIdx.x >> 6);   // 1024 waves total
    int b = threadIdx.x & 63;
    const float* w = Wdec + (size_t)g * 1024;
    float a0 = 0.f, a1 = 0.f, a2 = 0.f, a3 = 0.f;
    for (int k = 0; k < 1024; k += 4) {
        a0 += xinT[(1035 + k + 0) * 64 + b] * w[k + 0];
        a1 += xinT[(1035 + k + 1) * 64 + b] * w[k + 1];
        a2 += xinT[(1035 + k + 2) * 64 + b] * w[k + 2];
        a3 += xinT[(1035 + k + 3) * 64 + b] * w[k + 3];
    }
    decp[b * 1024 + g] = (a0 + a1) + (a2 + a3);
}

// ---------------------------------------------------------------------------
// k2: bf16 MFMA attn-score GEMM + fused tanh.w_val epilogue. (validated R2)
__global__ __launch_bounds__(256) void k2_scores(const unsigned short* __restrict__ encB,
                                                 const unsigned short* __restrict__ wencB,
                                                 const float* __restrict__ decp,
                                                 const float* __restrict__ wval,
                                                 float* __restrict__ part) {
    __shared__ short As[8192];       // 8 quads * 128 rows * 8 bf16 = 16 KB
    __shared__ short Bs[8192];
    __shared__ float rsum[2][128];

    const int m0 = blockIdx.x * 128;          // 256 M-tiles (128 | 512 => b uniform)
    const int n0 = blockIdx.y * 128;          // 8 N-tiles
    const int b  = m0 >> 9;
    const int tid  = threadIdx.x;
    const int wave = tid >> 6;
    const int lane = tid & 63;
    const int wr = wave >> 1;
    const int wc = wave & 1;
    const int q4 = lane >> 4;
    const int ml = lane & 15;

    f32x4 acc[4][4];
#pragma unroll
    for (int i = 0; i < 4; ++i)
#pragma unroll
        for (int j = 0; j < 4; ++j) acc[i][j] = (f32x4){0.f, 0.f, 0.f, 0.f};

    const unsigned short* aTile = encB  + (size_t)m0 * 1024;
    const unsigned short* bTile = wencB + (size_t)n0 * 1024;

    for (int k0 = 0; k0 < 1024; k0 += 64) {
        __syncthreads();
#pragma unroll
        for (int t = 0; t < 4; ++t) {
            int cc = t * 4 + wave;            // 16 chunks: q=cc>>1, mb=(cc&1)*64
            int q  = cc >> 1;
            int mb = (cc & 1) << 6;
            ASYNC_CP16(aTile + (size_t)(mb + lane) * 1024 + k0 + q * 8,
                       &As[(q * 128 + mb) * 8]);
            ASYNC_CP16(bTile + (size_t)(mb + lane) * 1024 + k0 + q * 8,
                       &Bs[(q * 128 + mb) * 8]);
        }
        __syncthreads();
#pragma unroll
        for (int s = 0; s < 2; ++s) {
            bf16x8 af[4], bfr[4];
#pragma unroll
            for (int i = 0; i < 4; ++i)
                af[i] = *(const bf16x8*)&As[((((s << 2) + q4) * 128) + wr * 64 + (i << 4) + ml) * 8];
#pragma unroll
            for (int j = 0; j < 4; ++j)
                bfr[j] = *(const bf16x8*)&Bs[((((s << 2) + q4) * 128) + wc * 64 + (j << 4) + ml) * 8];
#pragma unroll
            for (int i = 0; i < 4; ++i)
#pragma unroll
                for (int j = 0; j < 4; ++j)
                    acc[i][j] = __builtin_amdgcn_mfma_f32_16x16x32_bf16(af[i], bfr[j], acc[i][j], 0, 0, 0);
        }
    }

    float dpv[4], wvv[4];
#pragma unroll
    for (int j = 0; j < 4; ++j) {
        int n = n0 + wc * 64 + (j << 4) + ml;
        dpv[j] = decp[b * 1024 + n];
        wvv[j] = wval[n];
    }
#pragma unroll
    for (int i = 0; i < 4; ++i) {
#pragma unroll
        for (int r = 0; r < 4; ++r) {
            float p = 0.f;
#pragma unroll
            for (int j = 0; j < 4; ++j) p += tanhf(acc[i][j][r] + dpv[j]) * wvv[j];
            p += __shfl_xor(p, 1);
            p += __shfl_xor(p, 2);
            p += __shfl_xor(p, 4);
            p += __shfl_xor(p, 8);
            if (ml == 0) rsum[wc][wr * 64 + (i << 4) + q4 * 4 + r] = p;
        }
    }
    __syncthreads();
    if (tid < 128)
        part[(size_t)blockIdx.y * Mn + m0 + tid] = rsum[0][tid] + rsum[1][tid];
}

// ---------------------------------------------------------------------------
__device__ __forceinline__ float block_sum256(float v, float* red, int tid) {
#pragma unroll
    for (int off = 1; off < 64; off <<= 1) v += __shfl_xor(v, off);
    if ((tid & 63) == 0) red[tid >> 6] = v;
    __syncthreads();
    v = red[0] + red[1] + red[2] + red[3];
    __syncthreads();
    return v;
}

// k3a: sum 8 partial slices -> softmax over S -> attn_weight (out + ws)
__global__ __launch_bounds__(256) void k3a_softmax(const float* __restrict__ part,
                                                   float* __restrict__ wts,
                                                   float* __restrict__ out) {
    int b = blockIdx.x;
    int tid = threadIdx.x;
    __shared__ float red[8];
    int s0 = tid, s1 = tid + 256;
    float v0 = 0.f, v1 = 0.f;
#pragma unroll
    for (int nb = 0; nb < 8; ++nb) {
        v0 += part[(size_t)nb * Mn + b * 512 + s0];
        v1 += part[(size_t)nb * Mn + b * 512 + s1];
    }
    float mx = fmaxf(v0, v1);
#pragma unroll
    for (int off = 1; off < 64; off <<= 1) mx = fmaxf(mx, __shfl_xor(mx, off));
    if ((tid & 63) == 0) red[tid >> 6] = mx;
    __syncthreads();
    mx = fmaxf(fmaxf(red[0], red[1]), fmaxf(red[2], red[3]));
    __syncthreads();
    float e0 = __expf(v0 - mx), e1 = __expf(v1 - mx);
    float sm = block_sum256(e0 + e1, red, tid);
    float inv = 1.0f / sm;
    float w0 = e0 * inv, w1 = e1 * inv;
    wts[b * 512 + s0] = w0;
    wts[b * 512 + s1] = w1;
    out[OUT_AW + b * 512 + s0] = w0;
    out[OUT_AW + b * 512 + s1] = w1;
}

// k3b: context[b,h] = sum_s w[b,s] * encB[b,s,h]  (bf16 enc, 2 h per thread)
__global__ __launch_bounds__(256) void k3b_context(const unsigned short* __restrict__ encB,
                                                   const float* __restrict__ wts,
                                                   float* __restrict__ ctx) {
    int b = blockIdx.y;
    int h2 = (blockIdx.x * 256 + threadIdx.x) * 2;   // grid.x = 2
    const unsigned short* e = encB + (size_t)b * Sn * Hn + h2;
    const float* w = wts + b * 512;
    float a0 = 0.f, a1 = 0.f, b0 = 0.f, b1 = 0.f;
    for (int s = 0; s < 512; s += 2) {
        unsigned int p0 = *(const unsigned int*)(e + (size_t)(s + 0) * 1024);
        unsigned int p1 = *(const unsigned int*)(e + (size_t)(s + 1) * 1024);
        a0 += w[s + 0] * bf2f((unsigned short)(p0 & 0xffffu));
        b0 += w[s + 0] * bf2f((unsigned short)(p0 >> 16));
        a1 += w[s + 1] * bf2f((unsigned short)(p1 & 0xffffu));
        b1 += w[s + 1] * bf2f((unsigned short)(p1 >> 16));
    }
    ctx[b * 1024 + h2]     = a0 + a1;
    ctx[b * 1024 + h2 + 1] = b0 + b1;
}

// k4: sim[b,e'] = sum_e W_gate[e',e] * (ctx[b,:] . events[e,:])
__global__ __launch_bounds__(256) void k4_sim(const float* __restrict__ ctx,
                                              const float* __restrict__ events,
                                              const float* __restrict__ Wg,
                                              float* __restrict__ out) {
    int b = blockIdx.x;
    int tid = threadIdx.x, wv = tid >> 6, lane = tid & 63;
    __shared__ float tmp[16];
    const float* c = ctx + b * 1024;
    for (int e = wv; e < 10; e += 4) {
        const float* ev = events + e * 1024;
        float a = 0.f;
#pragma unroll
        for (int kk = 0; kk < 1024; kk += 64) a += c[kk + lane] * ev[kk + lane];
#pragma unroll
        for (int off = 1; off < 64; off <<= 1) a += __shfl_xor(a, off);
        if (lane == 0) tmp[e] = a;
    }
    __syncthreads();
    if (tid < 10) {
        float s2 = 0.f;
#pragma unroll
        for (int e = 0; e < 10; ++e) s2 += Wg[tid * 10 + e] * tmp[e];
        out[OUT_SIM + b * 10 + tid] = s2;
    }
}

// ---------------------------------------------------------------------------
// k_castW: WcatB[r][k] = bf16( k<1035 ? Wih[r][k] : k<2059 ? Whh[r][k-1035] : 0 )
__global__ __launch_bounds__(256) void k_castW(const float* __restrict__ Wih,
                                               const float* __restrict__ Whh,
                                               unsigned short* __restrict__ WcatB) {
    unsigned int idx = blockIdx.x * 256 + threadIdx.x;   // 4096*2112 = 8650752
    unsigned int r = idx / KP;
    unsigned int k = idx - r * KP;
    float v = 0.f;
    if (k < 1035)      v = Wih[(size_t)r * 1035 + k];
    else if (k < 2059) v = Whh[(size_t)r * 1024 + (k - 1035)];
    WcatB[idx] = f2bf(v);
}

// k_xinB: xinB[b][k] = bf16 of [ctx(1024), sim(10), x(1), h0(1024), pad]
__global__ __launch_bounds__(256) void k_xinB(const float* __restrict__ ctx,
                                              const float* __restrict__ simOut,
                                              const float* __restrict__ x,
                                              const float* __restrict__ h0,
                                              unsigned short* __restrict__ xinB) {
    unsigned int idx = blockIdx.x * 256 + threadIdx.x;   // 64*2112 = 135168
    unsigned int b = idx / KP;
    unsigned int k = idx - b * KP;
    float v = 0.f;
    if (k < 1024)       v = ctx[b * 1024 + k];
    else if (k < 1034)  v = simOut[b * 10 + (k - 1024)];
    else if (k == 1034) v = x[b];
    else if (k < 2059)  v = h0[b * 1024 + (k - 1035)];
    xinB[idx] = f2bf(v);
}

// ---------------------------------------------------------------------------
// k5_gemm: G[64,4096] = xinB[64,KP] . WcatB[4096,KP]^T  with split-K 8.
// M-tile 64, N-tile 128, BK=64; waves 2x2 (wave tile 32x64); same LDS scheme as k2.
__global__ __launch_bounds__(256) void k5_gemm(const unsigned short* __restrict__ xinB,
                                               const unsigned short* __restrict__ WcatB,
                                               float* __restrict__ gpart) {
    __shared__ short As[4096];       // 8 quads * 64 rows * 8 bf16 = 8 KB
    __shared__ short Bs[8192];       // 8 quads * 128 rows * 8 bf16 = 16 KB

    const int n0 = blockIdx.x * 128;              // 32 N-tiles
    const int sp = blockIdx.y;                    // 8 K-splits; steps 5,4,4,...
    const int kbeg   = (sp == 0) ? 0 : (5 + (sp - 1) * 4) * 64;
    const int ksteps = (sp == 0) ? 5 : 4;
    const int tid  = threadIdx.x;
    const int wave = tid >> 6;
    const int lane = tid & 63;
    const int wr = wave >> 1;                     // rows wr*32..+31
    const int wc = wave & 1;                      // cols wc*64..+63
    const int q4 = lane >> 4;
    const int ml = lane & 15;

    f32x4 acc[2][4];
#pragma unroll
    for (int i = 0; i < 2; ++i)
#pragma unroll
        for (int j = 0; j < 4; ++j) acc[i][j] = (f32x4){0.f, 0.f, 0.f, 0.f};

    const unsigned short* bTile = WcatB + (size_t)n0 * KP;

    for (int kk = 0; kk < ksteps; ++kk) {
        int k0 = kbeg + kk * 64;
        __syncthreads();
        // A: 8 chunks (one quad each, 64 rows = lanes)
#pragma unroll
        for (int t = 0; t < 2; ++t) {
            int q = wave * 2 + t;
            ASYNC_CP16(xinB + (size_t)lane * KP + k0 + q * 8, &As[(q * 64) * 8]);
        }
        // B: 16 chunks
#pragma unroll
        for (int t = 0; t < 4; ++t) {
            int cb = t * 4 + wave;
            int q  = cb >> 1;
            int mb = (cb & 1) << 6;
            ASYNC_CP16(bTile + (size_t)(mb + lane) * KP + k0 + q * 8,
                       &Bs[(q * 128 + mb) * 8]);
        }
        __syncthreads();
#pragma unroll
        for (int s = 0; s < 2; ++s) {
            bf16x8 af[2], bfr[4];
#pragma unroll
            for (int i = 0; i < 2; ++i)
                af[i] = *(const bf16x8*)&As[((((s << 2) + q4) * 64) + wr * 32 + (i << 4) + ml) * 8];
#pragma unroll
            for (int j = 0; j < 4; ++j)
                bfr[j] = *(const bf16x8*)&Bs[((((s << 2) + q4) * 128) + wc * 64 + (j << 4) + ml) * 8];
#pragma unroll
            for (int i = 0; i < 2; ++i)
#pragma unroll
                for (int j = 0; j < 4; ++j)
                    acc[i][j] = __builtin_amdgcn_mfma_f32_16x16x32_bf16(af[i], bfr[j], acc[i][j], 0, 0, 0);
        }
    }

    // write split partial: m = wr*32 + i*16 + q4*4 + r ; n = n0 + wc*64 + j*16 + ml
#pragma unroll
    for (int i = 0; i < 2; ++i)
#pragma unroll
        for (int j = 0; j < 4; ++j)
#pragma unroll
            for (int r = 0; r < 4; ++r) {
                int m = wr * 32 + (i << 4) + q4 * 4 + r;
                int n = n0 + wc * 64 + (j << 4) + ml;
                gpart[((size_t)sp * 64 + m) * 4096 + n] = acc[i][j][r];
            }
}

// k5_fin: gates = sum_sp gpart + biases; LSTM cell update -> h_new, c_new
__global__ __launch_bounds__(256) void k5_fin(const float* __restrict__ gpart,
                                              const float* __restrict__ bih,
                                              const float* __restrict__ bhh,
                                              const float* __restrict__ c0,
                                              float* __restrict__ out) {
    int idx = blockIdx.x * 256 + threadIdx.x;   // 65536: b,u
    int b = idx >> 10;
    int u = idx & 1023;
    float g[4];
#pragma unroll
    for (int gt = 0; gt < 4; ++gt) {
        int r = gt * 1024 + u;
        float a = bih[r] + bhh[r];
#pragma unroll
        for (int sp = 0; sp < 8; ++sp)
            a += gpart[((size_t)sp * 64 + b) * 4096 + r];
        g[gt] = a;
    }
    float cp = c0[b * 1024 + u];
    float si = 1.f / (1.f + __expf(-g[0]));
    float sf = 1.f / (1.f + __expf(-g[1]));
    float so = 1.f / (1.f + __expf(-g[3]));
    float cn = sf * cp + si * tanhf(g[2]);
    float hn = so * tanhf(cn);
    out[OUT_H + b * 1024 + u] = hn;
    out[OUT_C + b * 1024 + u] = cn;
}

// k6: LayerNorm(h_new) -> y ; fin[b] = y . W_fin + b_fin
__global__ __launch_bounds__(256) void k6_lnfin(const float* __restrict__ lng,
                                                const float* __restrict__ lnb,
                                                const float* __restrict__ Wfin,
                                                const float* __restrict__ bfin,
                                                float* __restrict__ out) {
    int b = blockIdx.x, tid = threadIdx.x;
    __shared__ float red[8];
    const float* h = out + OUT_H + b * 1024;
    float v0 = h[tid], v1 = h[tid + 256], v2 = h[tid + 512], v3 = h[tid + 768];
    float mu = block_sum256(v0 + v1 + v2 + v3, red, tid) * (1.f / 1024.f);
    float d0 = v0 - mu, d1 = v1 - mu, d2 = v2 - mu, d3 = v3 - mu;
    float var = block_sum256(d0 * d0 + d1 * d1 + d2 * d2 + d3 * d3, red, tid) * (1.f / 1024.f);
    float rstd = rsqrtf(var + 1e-5f);
    float acc = (d0 * rstd * lng[tid]       + lnb[tid])       * Wfin[tid]
              + (d1 * rstd * lng[tid + 256] + lnb[tid + 256]) * Wfin[tid + 256]
              + (d2 * rstd * lng[tid + 512] + lnb[tid + 512]) * Wfin[tid + 512]
              + (d3 * rstd * lng[tid + 768] + lnb[tid + 768]) * Wfin[tid + 768];
    acc = block_sum256(acc, red, tid);
    if (tid == 0) out[OUT_FIN + b] = acc + bfin[0];
}

// ---------------------------------------------------------------------------
extern "C" void kernel_launch(void* const* d_in, const int* in_sizes, int n_in,
                              void* d_out, int out_size, void* d_ws, size_t ws_size,
                              hipStream_t stream) {
    (void)in_sizes; (void)n_in; (void)out_size; (void)ws_size;
    const float* x    = (const float*)d_in[0];
    const float* h0   = (const float*)d_in[1];
    const float* c0   = (const float*)d_in[2];
    const float* enc  = (const float*)d_in[3];
    const float* Wenc = (const float*)d_in[4];
    const float* Wdec = (const float*)d_in[5];
    const float* wval = (const float*)d_in[6];
    const float* Wg   = (const float*)d_in[7];
    const float* ev   = (const float*)d_in[8];
    const float* Wih  = (const float*)d_in[9];
    const float* Whh  = (const float*)d_in[10];
    const float* bih  = (const float*)d_in[11];
    const float* bhh  = (const float*)d_in[12];
    const float* lng  = (const float*)d_in[13];
    const float* lnb  = (const float*)d_in[14];
    const float* Wfin = (const float*)d_in[15];
    const float* bfin = (const float*)d_in[16];

    float* out  = (float*)d_out;
    float* ws   = (float*)d_ws;
    unsigned short* encB  = (unsigned short*)(ws + WS_ENCB);
    unsigned short* wencB = (unsigned short*)(ws + WS_WENCB);
    float* decp = ws + WS_DECP;
    float* part = ws + WS_PART;
    float* ctx  = ws + WS_CTX;
    float* xinT = ws + WS_XINT;
    float* wts  = ws + WS_DECP;                       // alias: decp dead after k2
    unsigned short* WcatB = (unsigned short*)(ws + WS_WCATB);   // alias encB region
    float* gpart = ws + WS_GPART;                               // alias encB region
    unsigned short* xinB  = (unsigned short*)(ws + WS_XINB);    // alias encB region

    k_cast     <<<16896, 256, 0, stream>>>(enc, Wenc, encB, wencB);
    k0_h0T     <<<256, 256, 0, stream>>>(h0, xinT);
    k1_decproj <<<256, 256, 0, stream>>>(xinT, Wdec, decp);
    k2_scores  <<<dim3(256, 8), 256, 0, stream>>>(encB, wencB, decp, wval, part);
    k3a_softmax<<<64, 256, 0, stream>>>(part, wts, out);
    k3b_context<<<dim3(2, 64), 256, 0, stream>>>(encB, wts, ctx);
    k4_sim     <<<64, 256, 0, stream>>>(ctx, ev, Wg, out);
    // encB region is dead past this point -> safe to overwrite with LSTM buffers
    k_castW    <<<33792, 256, 0, stream>>>(Wih, Whh, WcatB);
    k_xinB     <<<528, 256, 0, stream>>>(ctx, out + OUT_SIM, x, h0, xinB);
    k5_gemm    <<<dim3(32, 8), 256, 0, stream>>>(xinB, WcatB, gpart);
    k5_fin     <<<256, 256, 0, stream>>>(gpart, bih, bhh, c0, out);
    k6_lnfin   <<<64, 256, 0, stream>>>(lng, lnb, Wfin, bfin, out);
}

// Round 4
// 466.647 us; speedup vs baseline: 2.6809x; 1.1222x over previous
//
#include <hip/hip_runtime.h>
#include <math.h>

// Problem dims
#define Bn 64
#define Sn 512
#define Hn 1024
#define En 10
#define Mn (Bn*Sn)          // 32768 rows of the attention GEMM
#define KIN 1035            // H + E + 1  (xin length)
#define KP  2112            // padded LSTM K: 2059 -> 33*64

// d_out flat offsets (floats): fin(64), h_new(65536), c_new(65536), attn_w(32768), sim(640)
#define OUT_FIN 0
#define OUT_H   64
#define OUT_C   65600
#define OUT_AW  131136
#define OUT_SIM 163904

// d_ws offsets (floats)
#define WS_ENCB  0                     // 32M bf16; dead after k3b -> LSTM aliases
#define WS_WENCB 16777216              // 1M bf16
#define WS_WTS   17301504              // 64*512 fp32 attn weights
#define WS_PART  17334272              // 8*32768 fp32 k2 partials; ctxp alias after k3a
#define WS_CTX   17596416              // 64*1024
#define WS_WDECB 17661952              // 1M bf16
#define WS_H0B   18186240              // 64K bf16
#define WS_DPART 18219008              // 4*64*1024 fp32
// end 18481152 floats = 73.9 MB
// --- aliases inside the (dead after k3b/k3c) encB region ---
#define WS_WCATB 0                     // 4096*2112 bf16
#define WS_GPART 4325376               // 8*64*4096 fp32
#define WS_XINB  6422528               // 64*2112 bf16
// --- ctxp aliases WS_PART (part dead after k3a): 4*64*1024 fp32 = 262144 ---

typedef __attribute__((ext_vector_type(8))) short bf16x8;
typedef __attribute__((ext_vector_type(4))) float f32x4;

#define ASYNC_CP16(gptr, lptr) \
  __builtin_amdgcn_global_load_lds((const __attribute__((address_space(1))) void*)(gptr), \
                                   (__attribute__((address_space(3))) void*)(lptr), 16, 0, 0)

static __device__ __forceinline__ unsigned short f2bf(float f) {
    union { float f; unsigned int u; } v; v.f = f;
    unsigned int r = (v.u + 0x7fffu + ((v.u >> 16) & 1u)) >> 16;
    return (unsigned short)r;
}
static __device__ __forceinline__ float bf2f(unsigned short h) {
    union { unsigned int u; float f; } v; v.u = ((unsigned int)h) << 16;
    return v.f;
}
// fast tanh: (e^{2x}-1)/(e^{2x}+1) via hw exp + hw rcp; clamp keeps e finite
static __device__ __forceinline__ float fast_tanh(float x) {
    float cx = fminf(15.f, fmaxf(-15.f, x));
    float e = __expf(2.f * cx);
    return (e - 1.f) * __builtin_amdgcn_rcpf(e + 1.f);
}

// ---------------------------------------------------------------------------
// k_cast: fp32->bf16 for enc, Wenc, Wdec, h0. 2048 elems/block.
__global__ __launch_bounds__(256) void k_cast(const float* __restrict__ enc,
                                              const float* __restrict__ Wenc,
                                              const float* __restrict__ Wdec,
                                              const float* __restrict__ h0,
                                              unsigned short* __restrict__ encB,
                                              unsigned short* __restrict__ wencB,
                                              unsigned short* __restrict__ wdecB,
                                              unsigned short* __restrict__ h0B) {
    int bid = blockIdx.x;
    const float* src; unsigned short* dst; size_t off;
    if (bid < 16384)      { src = enc;  dst = encB;  off = (size_t)bid * 2048; }
    else if (bid < 16896) { src = Wenc; dst = wencB; off = (size_t)(bid - 16384) * 2048; }
    else if (bid < 17408) { src = Wdec; dst = wdecB; off = (size_t)(bid - 16896) * 2048; }
    else                  { src = h0;   dst = h0B;   off = (size_t)(bid - 17408) * 2048; }
    off += (size_t)threadIdx.x * 8;
    float4 v0 = *(const float4*)(src + off);
    float4 v1 = *(const float4*)(src + off + 4);
    ushort4 a; a.x = f2bf(v0.x); a.y = f2bf(v0.y); a.z = f2bf(v0.z); a.w = f2bf(v0.w);
    ushort4 b; b.x = f2bf(v1.x); b.y = f2bf(v1.y); b.z = f2bf(v1.z); b.w = f2bf(v1.w);
    *(ushort4*)(dst + off)     = a;
    *(ushort4*)(dst + off + 4) = b;
}

// ---------------------------------------------------------------------------
// k1_gemm: dpart[sp][b][g] = partial of h0B[b,:] . wdecB[g,:]  (M=64,N=1024,K=1024)
// grid (8 N-tiles, 4 K-splits); block 64x128, waves 2x2 (tile 32x64), BK=64.
__global__ __launch_bounds__(256) void k1_gemm(const unsigned short* __restrict__ h0B,
                                               const unsigned short* __restrict__ wdecB,
                                               float* __restrict__ dpart) {
    __shared__ short As[4096];       // 8 quads * 64 rows * 8
    __shared__ short Bs[8192];       // 8 quads * 128 rows * 8

    const int n0 = blockIdx.x * 128;
    const int sp = blockIdx.y;                    // 4 K-splits x 4 BK-iters
    const int kbeg = sp * 256;
    const int tid  = threadIdx.x;
    const int wave = tid >> 6;
    const int lane = tid & 63;
    const int wr = wave >> 1;
    const int wc = wave & 1;
    const int q4 = lane >> 4;
    const int ml = lane & 15;

    f32x4 acc[2][4];
#pragma unroll
    for (int i = 0; i < 2; ++i)
#pragma unroll
        for (int j = 0; j < 4; ++j) acc[i][j] = (f32x4){0.f, 0.f, 0.f, 0.f};

    const unsigned short* bTile = wdecB + (size_t)n0 * 1024;

    for (int kk = 0; kk < 4; ++kk) {
        int k0 = kbeg + kk * 64;
        __syncthreads();
#pragma unroll
        for (int t = 0; t < 2; ++t) {
            int q = wave * 2 + t;
            ASYNC_CP16(h0B + (size_t)lane * 1024 + k0 + q * 8, &As[(q * 64) * 8]);
        }
#pragma unroll
        for (int t = 0; t < 4; ++t) {
            int cb = t * 4 + wave;
            int q  = cb >> 1;
            int mb = (cb & 1) << 6;
            ASYNC_CP16(bTile + (size_t)(mb + lane) * 1024 + k0 + q * 8,
                       &Bs[(q * 128 + mb) * 8]);
        }
        __syncthreads();
#pragma unroll
        for (int s = 0; s < 2; ++s) {
            bf16x8 af[2], bfr[4];
#pragma unroll
            for (int i = 0; i < 2; ++i)
                af[i] = *(const bf16x8*)&As[((((s << 2) + q4) * 64) + wr * 32 + (i << 4) + ml) * 8];
#pragma unroll
            for (int j = 0; j < 4; ++j)
                bfr[j] = *(const bf16x8*)&Bs[((((s << 2) + q4) * 128) + wc * 64 + (j << 4) + ml) * 8];
#pragma unroll
            for (int i = 0; i < 2; ++i)
#pragma unroll
                for (int j = 0; j < 4; ++j)
                    acc[i][j] = __builtin_amdgcn_mfma_f32_16x16x32_bf16(af[i], bfr[j], acc[i][j], 0, 0, 0);
        }
    }
#pragma unroll
    for (int i = 0; i < 2; ++i)
#pragma unroll
        for (int j = 0; j < 4; ++j)
#pragma unroll
            for (int r = 0; r < 4; ++r) {
                int m = wr * 32 + (i << 4) + q4 * 4 + r;
                int n = n0 + wc * 64 + (j << 4) + ml;
                dpart[((size_t)sp * 64 + m) * 1024 + n] = acc[i][j][r];
            }
}

// ---------------------------------------------------------------------------
// k2: bf16 MFMA attn-score GEMM + fused fast-tanh.w_val epilogue.
// 512 threads, 8 waves (4x2), wave tile 32x64 (acc=32 AGPR), BK=128, 64 KB LDS.
__global__ __launch_bounds__(512, 4) void k2_scores(const unsigned short* __restrict__ encB,
                                                    const unsigned short* __restrict__ wencB,
                                                    const float* __restrict__ dpart,
                                                    const float* __restrict__ wval,
                                                    float* __restrict__ part) {
    __shared__ short As[16384];      // 16 quads * 128 rows * 8 bf16 = 32 KB
    __shared__ short Bs[16384];      // 32 KB  (rsum aliases As after the loop)

    const int m0 = blockIdx.x * 128;          // 256 M-tiles (128 | 512 => b uniform)
    const int n0 = blockIdx.y * 128;          // 8 N-tiles
    const int b  = m0 >> 9;
    const int tid  = threadIdx.x;
    const int wave = tid >> 6;                // 0..7
    const int lane = tid & 63;
    const int wr = wave >> 1;                 // 0..3: rows wr*32..+31
    const int wc = wave & 1;                  // cols wc*64..+63
    const int q4 = lane >> 4;
    const int ml = lane & 15;

    f32x4 acc[2][4];
#pragma unroll
    for (int i = 0; i < 2; ++i)
#pragma unroll
        for (int j = 0; j < 4; ++j) acc[i][j] = (f32x4){0.f, 0.f, 0.f, 0.f};

    const unsigned short* aTile = encB  + (size_t)m0 * 1024;
    const unsigned short* bTile = wencB + (size_t)n0 * 1024;

    for (int k0 = 0; k0 < 1024; k0 += 128) {     // 8 iterations
        __syncthreads();
        // 64 chunks (A:32, B:32); 8 per wave
#pragma unroll
        for (int t = 0; t < 8; ++t) {
            int c = t * 8 + wave;
            if (c < 32) {
                int q  = c >> 1;
                int mb = (c & 1) << 6;
                ASYNC_CP16(aTile + (size_t)(mb + lane) * 1024 + k0 + q * 8,
                           &As[(q * 128 + mb) * 8]);
            } else {
                int c2 = c - 32;
                int q  = c2 >> 1;
                int mb = (c2 & 1) << 6;
                ASYNC_CP16(bTile + (size_t)(mb + lane) * 1024 + k0 + q * 8,
                           &Bs[(q * 128 + mb) * 8]);
            }
        }
        __syncthreads();
#pragma unroll
        for (int s = 0; s < 4; ++s) {
            bf16x8 af[2], bfr[4];
            int q = (s << 2) + q4;
#pragma unroll
            for (int i = 0; i < 2; ++i)
                af[i] = *(const bf16x8*)&As[((q * 128) + wr * 32 + (i << 4) + ml) * 8];
#pragma unroll
            for (int j = 0; j < 4; ++j)
                bfr[j] = *(const bf16x8*)&Bs[((q * 128) + wc * 64 + (j << 4) + ml) * 8];
#pragma unroll
            for (int i = 0; i < 2; ++i)
#pragma unroll
                for (int j = 0; j < 4; ++j)
                    acc[i][j] = __builtin_amdgcn_mfma_f32_16x16x32_bf16(af[i], bfr[j], acc[i][j], 0, 0, 0);
        }
    }

    // epilogue: dec_proj = sum of 4 k1 splits; rows of tanh()*wval reduced over 128 cols
    float dpv[4], wvv[4];
#pragma unroll
    for (int j = 0; j < 4; ++j) {
        int n = n0 + wc * 64 + (j << 4) + ml;
        float d = 0.f;
#pragma unroll
        for (int sp = 0; sp < 4; ++sp) d += dpart[((size_t)sp * 64 + b) * 1024 + n];
        dpv[j] = d;
        wvv[j] = wval[n];
    }
    __syncthreads();                 // all LDS reads done -> reuse As as rsum
    float* rsum = (float*)As;        // [2][128]
#pragma unroll
    for (int i = 0; i < 2; ++i) {
#pragma unroll
        for (int r = 0; r < 4; ++r) {
            float p = 0.f;
#pragma unroll
            for (int j = 0; j < 4; ++j) p += fast_tanh(acc[i][j][r] + dpv[j]) * wvv[j];
            p += __shfl_xor(p, 1);
            p += __shfl_xor(p, 2);
            p += __shfl_xor(p, 4);
            p += __shfl_xor(p, 8);
            if (ml == 0) rsum[wc * 128 + wr * 32 + (i << 4) + q4 * 4 + r] = p;
        }
    }
    __syncthreads();
    if (tid < 128)
        part[(size_t)blockIdx.y * Mn + m0 + tid] = rsum[tid] + rsum[128 + tid];
}

// ---------------------------------------------------------------------------
__device__ __forceinline__ float block_sum256(float v, float* red, int tid) {
#pragma unroll
    for (int off = 1; off < 64; off <<= 1) v += __shfl_xor(v, off);
    if ((tid & 63) == 0) red[tid >> 6] = v;
    __syncthreads();
    v = red[0] + red[1] + red[2] + red[3];
    __syncthreads();
    return v;
}

// k3a: sum 8 partial slices -> softmax over S -> attn_weight (out + ws)
__global__ __launch_bounds__(256) void k3a_softmax(const float* __restrict__ part,
                                                   float* __restrict__ wts,
                                                   float* __restrict__ out) {
    int b = blockIdx.x;
    int tid = threadIdx.x;
    __shared__ float red[8];
    int s0 = tid, s1 = tid + 256;
    float v0 = 0.f, v1 = 0.f;
#pragma unroll
    for (int nb = 0; nb < 8; ++nb) {
        v0 += part[(size_t)nb * Mn + b * 512 + s0];
        v1 += part[(size_t)nb * Mn + b * 512 + s1];
    }
    float mx = fmaxf(v0, v1);
#pragma unroll
    for (int off = 1; off < 64; off <<= 1) mx = fmaxf(mx, __shfl_xor(mx, off));
    if ((tid & 63) == 0) red[tid >> 6] = mx;
    __syncthreads();
    mx = fmaxf(fmaxf(red[0], red[1]), fmaxf(red[2], red[3]));
    __syncthreads();
    float e0 = __expf(v0 - mx), e1 = __expf(v1 - mx);
    float sm = block_sum256(e0 + e1, red, tid);
    float inv = 1.0f / sm;
    float w0 = e0 * inv, w1 = e1 * inv;
    wts[b * 512 + s0] = w0;
    wts[b * 512 + s1] = w1;
    out[OUT_AW + b * 512 + s0] = w0;
    out[OUT_AW + b * 512 + s1] = w1;
}

// k3b: ctxp[sc][b][h] = sum_{s in chunk sc} w[b,s] * encB[b,s,h]  (4 S-chunks of 128)
__global__ __launch_bounds__(256) void k3b_context(const unsigned short* __restrict__ encB,
                                                   const float* __restrict__ wts,
                                                   float* __restrict__ ctxp) {
    int b  = blockIdx.y;
    int sc = blockIdx.x >> 1;                        // 0..3
    int hh = blockIdx.x & 1;                         // h half
    int h2 = (hh * 256 + threadIdx.x) * 2;           // 0..1022
    const unsigned short* e = encB + (size_t)b * Sn * Hn + (size_t)sc * 128 * Hn + h2;
    const float* w = wts + b * 512 + sc * 128;
    float a0 = 0.f, a1 = 0.f, b0 = 0.f, b1 = 0.f;
    for (int s = 0; s < 128; s += 2) {
        unsigned int p0 = *(const unsigned int*)(e + (size_t)(s + 0) * 1024);
        unsigned int p1 = *(const unsigned int*)(e + (size_t)(s + 1) * 1024);
        a0 += w[s + 0] * bf2f((unsigned short)(p0 & 0xffffu));
        b0 += w[s + 0] * bf2f((unsigned short)(p0 >> 16));
        a1 += w[s + 1] * bf2f((unsigned short)(p1 & 0xffffu));
        b1 += w[s + 1] * bf2f((unsigned short)(p1 >> 16));
    }
    ctxp[((size_t)sc * 64 + b) * 1024 + h2]     = a0 + a1;
    ctxp[((size_t)sc * 64 + b) * 1024 + h2 + 1] = b0 + b1;
}

// k3c: ctx = sum of 4 S-chunk partials
__global__ __launch_bounds__(256) void k3c_reduce(const float* __restrict__ ctxp,
                                                  float* __restrict__ ctx) {
    int idx = blockIdx.x * 256 + threadIdx.x;        // 65536
    ctx[idx] = ctxp[idx] + ctxp[65536 + idx] + ctxp[131072 + idx] + ctxp[196608 + idx];
}

// k4: sim[b,e'] = sum_e W_gate[e',e] * (ctx[b,:] . events[e,:])
__global__ __launch_bounds__(256) void k4_sim(const float* __restrict__ ctx,
                                              const float* __restrict__ events,
                                              const float* __restrict__ Wg,
                                              float* __restrict__ out) {
    int b = blockIdx.x;
    int tid = threadIdx.x, wv = tid >> 6, lane = tid & 63;
    __shared__ float tmp[16];
    const float* c = ctx + b * 1024;
    for (int e = wv; e < 10; e += 4) {
        const float* ev = events + e * 1024;
        float a = 0.f;
#pragma unroll
        for (int kk = 0; kk < 1024; kk += 64) a += c[kk + lane] * ev[kk + lane];
#pragma unroll
        for (int off = 1; off < 64; off <<= 1) a += __shfl_xor(a, off);
        if (lane == 0) tmp[e] = a;
    }
    __syncthreads();
    if (tid < 10) {
        float s2 = 0.f;
#pragma unroll
        for (int e = 0; e < 10; ++e) s2 += Wg[tid * 10 + e] * tmp[e];
        out[OUT_SIM + b * 10 + tid] = s2;
    }
}

// ---------------------------------------------------------------------------
// k_castW: WcatB[r][k] = bf16( k<1035 ? Wih[r][k] : k<2059 ? Whh[r][k-1035] : 0 )
__global__ __launch_bounds__(256) void k_castW(const float* __restrict__ Wih,
                                               const float* __restrict__ Whh,
                                               unsigned short* __restrict__ WcatB) {
    unsigned int idx = blockIdx.x * 256 + threadIdx.x;   // 4096*2112
    unsigned int r = idx / KP;
    unsigned int k = idx - r * KP;
    float v = 0.f;
    if (k < 1035)      v = Wih[(size_t)r * 1035 + k];
    else if (k < 2059) v = Whh[(size_t)r * 1024 + (k - 1035)];
    WcatB[idx] = f2bf(v);
}

// k_xinB: xinB[b][k] = bf16 of [ctx(1024), sim(10), x(1), h0(1024), pad]
__global__ __launch_bounds__(256) void k_xinB(const float* __restrict__ ctx,
                                              const float* __restrict__ simOut,
                                              const float* __restrict__ x,
                                              const float* __restrict__ h0,
                                              unsigned short* __restrict__ xinB) {
    unsigned int idx = blockIdx.x * 256 + threadIdx.x;   // 64*2112
    unsigned int b = idx / KP;
    unsigned int k = idx - b * KP;
    float v = 0.f;
    if (k < 1024)       v = ctx[b * 1024 + k];
    else if (k < 1034)  v = simOut[b * 10 + (k - 1024)];
    else if (k == 1034) v = x[b];
    else if (k < 2059)  v = h0[b * 1024 + (k - 1035)];
    xinB[idx] = f2bf(v);
}

// ---------------------------------------------------------------------------
// k5_gemm: G[64,4096] = xinB[64,KP] . WcatB[4096,KP]^T  with split-K 8. (validated R3)
__global__ __launch_bounds__(256) void k5_gemm(const unsigned short* __restrict__ xinB,
                                               const unsigned short* __restrict__ WcatB,
                                               float* __restrict__ gpart) {
    __shared__ short As[4096];
    __shared__ short Bs[8192];

    const int n0 = blockIdx.x * 128;
    const int sp = blockIdx.y;
    const int kbeg   = (sp == 0) ? 0 : (5 + (sp - 1) * 4) * 64;
    const int ksteps = (sp == 0) ? 5 : 4;
    const int tid  = threadIdx.x;
    const int wave = tid >> 6;
    const int lane = tid & 63;
    const int wr = wave >> 1;
    const int wc = wave & 1;
    const int q4 = lane >> 4;
    const int ml = lane & 15;

    f32x4 acc[2][4];
#pragma unroll
    for (int i = 0; i < 2; ++i)
#pragma unroll
        for (int j = 0; j < 4; ++j) acc[i][j] = (f32x4){0.f, 0.f, 0.f, 0.f};

    const unsigned short* bTile = WcatB + (size_t)n0 * KP;

    for (int kk = 0; kk < ksteps; ++kk) {
        int k0 = kbeg + kk * 64;
        __syncthreads();
#pragma unroll
        for (int t = 0; t < 2; ++t) {
            int q = wave * 2 + t;
            ASYNC_CP16(xinB + (size_t)lane * KP + k0 + q * 8, &As[(q * 64) * 8]);
        }
#pragma unroll
        for (int t = 0; t < 4; ++t) {
            int cb = t * 4 + wave;
            int q  = cb >> 1;
            int mb = (cb & 1) << 6;
            ASYNC_CP16(bTile + (size_t)(mb + lane) * KP + k0 + q * 8,
                       &Bs[(q * 128 + mb) * 8]);
        }
        __syncthreads();
#pragma unroll
        for (int s = 0; s < 2; ++s) {
            bf16x8 af[2], bfr[4];
#pragma unroll
            for (int i = 0; i < 2; ++i)
                af[i] = *(const bf16x8*)&As[((((s << 2) + q4) * 64) + wr * 32 + (i << 4) + ml) * 8];
#pragma unroll
            for (int j = 0; j < 4; ++j)
                bfr[j] = *(const bf16x8*)&Bs[((((s << 2) + q4) * 128) + wc * 64 + (j << 4) + ml) * 8];
#pragma unroll
            for (int i = 0; i < 2; ++i)
#pragma unroll
                for (int j = 0; j < 4; ++j)
                    acc[i][j] = __builtin_amdgcn_mfma_f32_16x16x32_bf16(af[i], bfr[j], acc[i][j], 0, 0, 0);
        }
    }
#pragma unroll
    for (int i = 0; i < 2; ++i)
#pragma unroll
        for (int j = 0; j < 4; ++j)
#pragma unroll
            for (int r = 0; r < 4; ++r) {
                int m = wr * 32 + (i << 4) + q4 * 4 + r;
                int n = n0 + wc * 64 + (j << 4) + ml;
                gpart[((size_t)sp * 64 + m) * 4096 + n] = acc[i][j][r];
            }
}

// k5_fin: gates = sum_sp gpart + biases; LSTM cell update -> h_new, c_new
__global__ __launch_bounds__(256) void k5_fin(const float* __restrict__ gpart,
                                              const float* __restrict__ bih,
                                              const float* __restrict__ bhh,
                                              const float* __restrict__ c0,
                                              float* __restrict__ out) {
    int idx = blockIdx.x * 256 + threadIdx.x;
    int b = idx >> 10;
    int u = idx & 1023;
    float g[4];
#pragma unroll
    for (int gt = 0; gt < 4; ++gt) {
        int r = gt * 1024 + u;
        float a = bih[r] + bhh[r];
#pragma unroll
        for (int sp = 0; sp < 8; ++sp)
            a += gpart[((size_t)sp * 64 + b) * 4096 + r];
        g[gt] = a;
    }
    float cp = c0[b * 1024 + u];
    float si = 1.f / (1.f + __expf(-g[0]));
    float sf = 1.f / (1.f + __expf(-g[1]));
    float so = 1.f / (1.f + __expf(-g[3]));
    float cn = sf * cp + si * tanhf(g[2]);
    float hn = so * tanhf(cn);
    out[OUT_H + b * 1024 + u] = hn;
    out[OUT_C + b * 1024 + u] = cn;
}

// k6: LayerNorm(h_new) -> y ; fin[b] = y . W_fin + b_fin
__global__ __launch_bounds__(256) void k6_lnfin(const float* __restrict__ lng,
                                                const float* __restrict__ lnb,
                                                const float* __restrict__ Wfin,
                                                const float* __restrict__ bfin,
                                                float* __restrict__ out) {
    int b = blockIdx.x, tid = threadIdx.x;
    __shared__ float red[8];
    const float* h = out + OUT_H + b * 1024;
    float v0 = h[tid], v1 = h[tid + 256], v2 = h[tid + 512], v3 = h[tid + 768];
    float mu = block_sum256(v0 + v1 + v2 + v3, red, tid) * (1.f / 1024.f);
    float d0 = v0 - mu, d1 = v1 - mu, d2 = v2 - mu, d3 = v3 - mu;
    float var = block_sum256(d0 * d0 + d1 * d1 + d2 * d2 + d3 * d3, red, tid) * (1.f / 1024.f);
    float rstd = rsqrtf(var + 1e-5f);
    float acc = (d0 * rstd * lng[tid]       + lnb[tid])       * Wfin[tid]
              + (d1 * rstd * lng[tid + 256] + lnb[tid + 256]) * Wfin[tid + 256]
              + (d2 * rstd * lng[tid + 512] + lnb[tid + 512]) * Wfin[tid + 512]
              + (d3 * rstd * lng[tid + 768] + lnb[tid + 768]) * Wfin[tid + 768];
    acc = block_sum256(acc, red, tid);
    if (tid == 0) out[OUT_FIN + b] = acc + bfin[0];
}

// ---------------------------------------------------------------------------
extern "C" void kernel_launch(void* const* d_in, const int* in_sizes, int n_in,
                              void* d_out, int out_size, void* d_ws, size_t ws_size,
                              hipStream_t stream) {
    (void)in_sizes; (void)n_in; (void)out_size; (void)ws_size;
    const float* x    = (const float*)d_in[0];
    const float* h0   = (const float*)d_in[1];
    const float* c0   = (const float*)d_in[2];
    const float* enc  = (const float*)d_in[3];
    const float* Wenc = (const float*)d_in[4];
    const float* Wdec = (const float*)d_in[5];
    const float* wval = (const float*)d_in[6];
    const float* Wg   = (const float*)d_in[7];
    const float* ev   = (const float*)d_in[8];
    const float* Wih  = (const float*)d_in[9];
    const float* Whh  = (const float*)d_in[10];
    const float* bih  = (const float*)d_in[11];
    const float* bhh  = (const float*)d_in[12];
    const float* lng  = (const float*)d_in[13];
    const float* lnb  = (const float*)d_in[14];
    const float* Wfin = (const float*)d_in[15];
    const float* bfin = (const float*)d_in[16];

    float* out  = (float*)d_out;
    float* ws   = (float*)d_ws;
    unsigned short* encB  = (unsigned short*)(ws + WS_ENCB);
    unsigned short* wencB = (unsigned short*)(ws + WS_WENCB);
    unsigned short* wdecB = (unsigned short*)(ws + WS_WDECB);
    unsigned short* h0B   = (unsigned short*)(ws + WS_H0B);
    float* dpart = ws + WS_DPART;
    float* wts   = ws + WS_WTS;
    float* part  = ws + WS_PART;
    float* ctxp  = ws + WS_PART;                                // alias: part dead after k3a
    float* ctx   = ws + WS_CTX;
    unsigned short* WcatB = (unsigned short*)(ws + WS_WCATB);   // alias encB (dead after k3b)
    float* gpart = ws + WS_GPART;                               // alias encB
    unsigned short* xinB  = (unsigned short*)(ws + WS_XINB);    // alias encB

    k_cast     <<<17440, 256, 0, stream>>>(enc, Wenc, Wdec, h0, encB, wencB, wdecB, h0B);
    k1_gemm    <<<dim3(8, 4), 256, 0, stream>>>(h0B, wdecB, dpart);
    k2_scores  <<<dim3(256, 8), 512, 0, stream>>>(encB, wencB, dpart, wval, part);
    k3a_softmax<<<64, 256, 0, stream>>>(part, wts, out);
    k3b_context<<<dim3(8, 64), 256, 0, stream>>>(encB, wts, ctxp);
    k3c_reduce <<<256, 256, 0, stream>>>(ctxp, ctx);
    k4_sim     <<<64, 256, 0, stream>>>(ctx, ev, Wg, out);
    // encB region dead past k3b -> safe for LSTM buffers
    k_castW    <<<33792, 256, 0, stream>>>(Wih, Whh, WcatB);
    k_xinB     <<<528, 256, 0, stream>>>(ctx, out + OUT_SIM, x, h0, xinB);
    k5_gemm    <<<dim3(32, 8), 256, 0, stream>>>(xinB, WcatB, gpart);
    k5_fin     <<<256, 256, 0, stream>>>(gpart, bih, bhh, c0, out);
    k6_lnfin   <<<64, 256, 0, stream>>>(lng, lnb, Wfin, bfin, out);
}

// Round 5
// 462.846 us; speedup vs baseline: 2.7030x; 1.0082x over previous
//
#include <hip/hip_runtime.h>
#include <math.h>

// Problem dims
#define Bn 64
#define Sn 512
#define Hn 1024
#define En 10
#define Mn (Bn*Sn)          // 32768 rows of the attention GEMM
#define KIN 1035            // H + E + 1  (xin length)
#define KP  2112            // padded LSTM K: 2059 -> 33*64

// d_out flat offsets (floats): fin(64), h_new(65536), c_new(65536), attn_w(32768), sim(640)
#define OUT_FIN 0
#define OUT_H   64
#define OUT_C   65600
#define OUT_AW  131136
#define OUT_SIM 163904

// d_ws offsets (floats)
#define WS_ENCB  0                     // 32M bf16; dead after k3b -> LSTM aliases
#define WS_WENCB 16777216              // 1M bf16
#define WS_WTS   17301504              // 64*512 fp32
#define WS_PART  17334272              // 8*32768 fp32 (k2 partials, dead after k3a)
#define WS_CTXP  17334272              // 8*64*1024 fp32 = 524288 (alias over PART; k3b after k3a)
#define WS_WDECB 17858560              // 1M bf16 = 524288 floats (dead after k1_gemm)
#define WS_H0B   18382848              // 64K bf16 = 32768 floats
#define WS_DPART 18415616              // 8*64*1024 fp32 = 524288
// end 18939904 floats = 75.8 MB
// --- aliases inside the (dead after k3b) encB region ---
#define WS_WCATB 0                     // 4096*2112 bf16
#define WS_GPART 4325376               // 8*64*4096 fp32
#define WS_XINB  6422528               // 64*2112 bf16

typedef __attribute__((ext_vector_type(8))) short bf16x8;
typedef __attribute__((ext_vector_type(4))) float f32x4;

#define ASYNC_CP16(gptr, lptr) \
  __builtin_amdgcn_global_load_lds((const __attribute__((address_space(1))) void*)(gptr), \
                                   (__attribute__((address_space(3))) void*)(lptr), 16, 0, 0)

static __device__ __forceinline__ unsigned short f2bf(float f) {
    union { float f; unsigned int u; } v; v.f = f;
    unsigned int r = (v.u + 0x7fffu + ((v.u >> 16) & 1u)) >> 16;
    return (unsigned short)r;
}
static __device__ __forceinline__ float bf2f(unsigned short h) {
    union { unsigned int u; float f; } v; v.u = ((unsigned int)h) << 16;
    return v.f;
}
// fast tanh: (e^{2x}-1)/(e^{2x}+1) via hw exp + hw rcp; clamp keeps e finite
static __device__ __forceinline__ float fast_tanh(float x) {
    float cx = fminf(15.f, fmaxf(-15.f, x));
    float e = __expf(2.f * cx);
    return (e - 1.f) * __builtin_amdgcn_rcpf(e + 1.f);
}

// ---------------------------------------------------------------------------
// k_cast: fp32->bf16 for enc, Wenc, Wdec, h0. 2048 elems/block.
__global__ __launch_bounds__(256) void k_cast(const float* __restrict__ enc,
                                              const float* __restrict__ Wenc,
                                              const float* __restrict__ Wdec,
                                              const float* __restrict__ h0,
                                              unsigned short* __restrict__ encB,
                                              unsigned short* __restrict__ wencB,
                                              unsigned short* __restrict__ wdecB,
                                              unsigned short* __restrict__ h0B) {
    int bid = blockIdx.x;
    const float* src; unsigned short* dst; size_t off;
    if (bid < 16384)      { src = enc;  dst = encB;  off = (size_t)bid * 2048; }
    else if (bid < 16896) { src = Wenc; dst = wencB; off = (size_t)(bid - 16384) * 2048; }
    else if (bid < 17408) { src = Wdec; dst = wdecB; off = (size_t)(bid - 16896) * 2048; }
    else                  { src = h0;   dst = h0B;   off = (size_t)(bid - 17408) * 2048; }
    off += (size_t)threadIdx.x * 8;
    float4 v0 = *(const float4*)(src + off);
    float4 v1 = *(const float4*)(src + off + 4);
    ushort4 a; a.x = f2bf(v0.x); a.y = f2bf(v0.y); a.z = f2bf(v0.z); a.w = f2bf(v0.w);
    ushort4 b; b.x = f2bf(v1.x); b.y = f2bf(v1.y); b.z = f2bf(v1.z); b.w = f2bf(v1.w);
    *(ushort4*)(dst + off)     = a;
    *(ushort4*)(dst + off + 4) = b;
}

// ---------------------------------------------------------------------------
// k1_gemm: dpart[sp][b][g] = partial of h0B[b,:] . wdecB[g,:]  (M=64,N=1024,K=1024)
// grid (8 N-tiles, 8 K-splits); block 64x128, waves 2x2 (tile 32x64), BK=64, 2 iters.
__global__ __launch_bounds__(256) void k1_gemm(const unsigned short* __restrict__ h0B,
                                               const unsigned short* __restrict__ wdecB,
                                               float* __restrict__ dpart) {
    __shared__ short As[4096];       // 8 quads * 64 rows * 8
    __shared__ short Bs[8192];       // 8 quads * 128 rows * 8

    const int n0 = blockIdx.x * 128;
    const int sp = blockIdx.y;                    // 8 K-splits x 2 BK-iters
    const int kbeg = sp * 128;
    const int tid  = threadIdx.x;
    const int wave = tid >> 6;
    const int lane = tid & 63;
    const int wr = wave >> 1;
    const int wc = wave & 1;
    const int q4 = lane >> 4;
    const int ml = lane & 15;

    f32x4 acc[2][4];
#pragma unroll
    for (int i = 0; i < 2; ++i)
#pragma unroll
        for (int j = 0; j < 4; ++j) acc[i][j] = (f32x4){0.f, 0.f, 0.f, 0.f};

    const unsigned short* bTile = wdecB + (size_t)n0 * 1024;

    for (int kk = 0; kk < 2; ++kk) {
        int k0 = kbeg + kk * 64;
        __syncthreads();
#pragma unroll
        for (int t = 0; t < 2; ++t) {
            int q = wave * 2 + t;
            ASYNC_CP16(h0B + (size_t)lane * 1024 + k0 + q * 8, &As[(q * 64) * 8]);
        }
#pragma unroll
        for (int t = 0; t < 4; ++t) {
            int cb = t * 4 + wave;
            int q  = cb >> 1;
            int mb = (cb & 1) << 6;
            ASYNC_CP16(bTile + (size_t)(mb + lane) * 1024 + k0 + q * 8,
                       &Bs[(q * 128 + mb) * 8]);
        }
        __syncthreads();
#pragma unroll
        for (int s = 0; s < 2; ++s) {
            bf16x8 af[2], bfr[4];
#pragma unroll
            for (int i = 0; i < 2; ++i)
                af[i] = *(const bf16x8*)&As[((((s << 2) + q4) * 64) + wr * 32 + (i << 4) + ml) * 8];
#pragma unroll
            for (int j = 0; j < 4; ++j)
                bfr[j] = *(const bf16x8*)&Bs[((((s << 2) + q4) * 128) + wc * 64 + (j << 4) + ml) * 8];
#pragma unroll
            for (int i = 0; i < 2; ++i)
#pragma unroll
                for (int j = 0; j < 4; ++j)
                    acc[i][j] = __builtin_amdgcn_mfma_f32_16x16x32_bf16(af[i], bfr[j], acc[i][j], 0, 0, 0);
        }
    }
#pragma unroll
    for (int i = 0; i < 2; ++i)
#pragma unroll
        for (int j = 0; j < 4; ++j)
#pragma unroll
            for (int r = 0; r < 4; ++r) {
                int m = wr * 32 + (i << 4) + q4 * 4 + r;
                int n = n0 + wc * 64 + (j << 4) + ml;
                dpart[((size_t)sp * 64 + m) * 1024 + n] = acc[i][j][r];
            }
}

// ---------------------------------------------------------------------------
// k2: bf16 MFMA attn-score GEMM + fused fast-tanh.w_val epilogue.
// 512 threads, 8 waves (4x2), wave tile 32x64, BK=128, 64 KB LDS.
// Grid 2048 1-D, n0 = bid&7 (A-sharing blocks dispatch-adjacent -> L3/L2 reuse).
__global__ __launch_bounds__(512, 4) void k2_scores(const unsigned short* __restrict__ encB,
                                                    const unsigned short* __restrict__ wencB,
                                                    const float* __restrict__ dpart,
                                                    const float* __restrict__ wval,
                                                    float* __restrict__ part) {
    __shared__ short As[16384];      // 16 quads * 128 rows * 8 bf16 = 32 KB
    __shared__ short Bs[16384];      // 32 KB  (rsum aliases As after the loop)

    const int bid = blockIdx.x;               // 2048
    const int m0 = (bid >> 3) * 128;          // 256 M-tiles (128 | 512 => b uniform)
    const int nb = bid & 7;                   // 8 N-tiles, fastest -> concurrent A-sharing
    const int n0 = nb * 128;
    const int b  = m0 >> 9;
    const int tid  = threadIdx.x;
    const int wave = tid >> 6;                // 0..7
    const int lane = tid & 63;
    const int wr = wave >> 1;                 // 0..3: rows wr*32..+31
    const int wc = wave & 1;                  // cols wc*64..+63
    const int q4 = lane >> 4;
    const int ml = lane & 15;

    f32x4 acc[2][4];
#pragma unroll
    for (int i = 0; i < 2; ++i)
#pragma unroll
        for (int j = 0; j < 4; ++j) acc[i][j] = (f32x4){0.f, 0.f, 0.f, 0.f};

    const unsigned short* aTile = encB  + (size_t)m0 * 1024;
    const unsigned short* bTile = wencB + (size_t)n0 * 1024;

    for (int k0 = 0; k0 < 1024; k0 += 128) {     // 8 iterations
        __syncthreads();
#pragma unroll
        for (int t = 0; t < 8; ++t) {
            int c = t * 8 + wave;
            if (c < 32) {
                int q  = c >> 1;
                int mb = (c & 1) << 6;
                ASYNC_CP16(aTile + (size_t)(mb + lane) * 1024 + k0 + q * 8,
                           &As[(q * 128 + mb) * 8]);
            } else {
                int c2 = c - 32;
                int q  = c2 >> 1;
                int mb = (c2 & 1) << 6;
                ASYNC_CP16(bTile + (size_t)(mb + lane) * 1024 + k0 + q * 8,
                           &Bs[(q * 128 + mb) * 8]);
            }
        }
        __syncthreads();
#pragma unroll
        for (int s = 0; s < 4; ++s) {
            bf16x8 af[2], bfr[4];
            int q = (s << 2) + q4;
#pragma unroll
            for (int i = 0; i < 2; ++i)
                af[i] = *(const bf16x8*)&As[((q * 128) + wr * 32 + (i << 4) + ml) * 8];
#pragma unroll
            for (int j = 0; j < 4; ++j)
                bfr[j] = *(const bf16x8*)&Bs[((q * 128) + wc * 64 + (j << 4) + ml) * 8];
#pragma unroll
            for (int i = 0; i < 2; ++i)
#pragma unroll
                for (int j = 0; j < 4; ++j)
                    acc[i][j] = __builtin_amdgcn_mfma_f32_16x16x32_bf16(af[i], bfr[j], acc[i][j], 0, 0, 0);
        }
    }

    // epilogue: dec_proj = sum of 8 k1 splits; rows of tanh()*wval reduced over 128 cols
    float dpv[4], wvv[4];
#pragma unroll
    for (int j = 0; j < 4; ++j) {
        int n = n0 + wc * 64 + (j << 4) + ml;
        float d = 0.f;
#pragma unroll
        for (int sp = 0; sp < 8; ++sp) d += dpart[((size_t)sp * 64 + b) * 1024 + n];
        dpv[j] = d;
        wvv[j] = wval[n];
    }
    __syncthreads();                 // all LDS reads done -> reuse As as rsum
    float* rsum = (float*)As;        // [2][128]
#pragma unroll
    for (int i = 0; i < 2; ++i) {
#pragma unroll
        for (int r = 0; r < 4; ++r) {
            float p = 0.f;
#pragma unroll
            for (int j = 0; j < 4; ++j) p += fast_tanh(acc[i][j][r] + dpv[j]) * wvv[j];
            p += __shfl_xor(p, 1);
            p += __shfl_xor(p, 2);
            p += __shfl_xor(p, 4);
            p += __shfl_xor(p, 8);
            if (ml == 0) rsum[wc * 128 + wr * 32 + (i << 4) + q4 * 4 + r] = p;
        }
    }
    __syncthreads();
    if (tid < 128)
        part[(size_t)nb * Mn + m0 + tid] = rsum[tid] + rsum[128 + tid];
}

// ---------------------------------------------------------------------------
__device__ __forceinline__ float block_sum256(float v, float* red, int tid) {
#pragma unroll
    for (int off = 1; off < 64; off <<= 1) v += __shfl_xor(v, off);
    if ((tid & 63) == 0) red[tid >> 6] = v;
    __syncthreads();
    v = red[0] + red[1] + red[2] + red[3];
    __syncthreads();
    return v;
}

// k3a: sum 8 partial slices -> softmax over S -> attn_weight (out + ws)
__global__ __launch_bounds__(256) void k3a_softmax(const float* __restrict__ part,
                                                   float* __restrict__ wts,
                                                   float* __restrict__ out) {
    int b = blockIdx.x;
    int tid = threadIdx.x;
    __shared__ float red[8];
    int s0 = tid, s1 = tid + 256;
    float v0 = 0.f, v1 = 0.f;
#pragma unroll
    for (int nb = 0; nb < 8; ++nb) {
        v0 += part[(size_t)nb * Mn + b * 512 + s0];
        v1 += part[(size_t)nb * Mn + b * 512 + s1];
    }
    float mx = fmaxf(v0, v1);
#pragma unroll
    for (int off = 1; off < 64; off <<= 1) mx = fmaxf(mx, __shfl_xor(mx, off));
    if ((tid & 63) == 0) red[tid >> 6] = mx;
    __syncthreads();
    mx = fmaxf(fmaxf(red[0], red[1]), fmaxf(red[2], red[3]));
    __syncthreads();
    float e0 = __expf(v0 - mx), e1 = __expf(v1 - mx);
    float sm = block_sum256(e0 + e1, red, tid);
    float inv = 1.0f / sm;
    float w0 = e0 * inv, w1 = e1 * inv;
    wts[b * 512 + s0] = w0;
    wts[b * 512 + s1] = w1;
    out[OUT_AW + b * 512 + s0] = w0;
    out[OUT_AW + b * 512 + s1] = w1;
}

// k3b: ctxp[sc][b][h] = sum_{s in 64-chunk sc} w[b,s] * encB[b,s,h]  (8 S-chunks)
__global__ __launch_bounds__(256) void k3b_context(const unsigned short* __restrict__ encB,
                                                   const float* __restrict__ wts,
                                                   float* __restrict__ ctxp) {
    int b  = blockIdx.y;
    int sc = blockIdx.x >> 1;                        // 0..7
    int hh = blockIdx.x & 1;                         // h half
    int h2 = (hh * 256 + threadIdx.x) * 2;           // 0..1022
    const unsigned short* e = encB + (size_t)b * Sn * Hn + (size_t)sc * 64 * Hn + h2;
    const float* w = wts + b * 512 + sc * 64;
    float a0 = 0.f, a1 = 0.f, b0 = 0.f, b1 = 0.f;
    for (int s = 0; s < 64; s += 2) {
        unsigned int p0 = *(const unsigned int*)(e + (size_t)(s + 0) * 1024);
        unsigned int p1 = *(const unsigned int*)(e + (size_t)(s + 1) * 1024);
        a0 += w[s + 0] * bf2f((unsigned short)(p0 & 0xffffu));
        b0 += w[s + 0] * bf2f((unsigned short)(p0 >> 16));
        a1 += w[s + 1] * bf2f((unsigned short)(p1 & 0xffffu));
        b1 += w[s + 1] * bf2f((unsigned short)(p1 >> 16));
    }
    ctxp[((size_t)sc * 64 + b) * 1024 + h2]     = a0 + a1;
    ctxp[((size_t)sc * 64 + b) * 1024 + h2 + 1] = b0 + b1;
}

// k4: ctx assembled in LDS from 8 ctxp chunks; sim[b,e'] = W_gate . (ctx . events^T)
__global__ __launch_bounds__(256) void k4_sim(const float* __restrict__ ctxp,
                                              const float* __restrict__ events,
                                              const float* __restrict__ Wg,
                                              float* __restrict__ out) {
    int b = blockIdx.x;
    int tid = threadIdx.x, wv = tid >> 6, lane = tid & 63;
    __shared__ float cl[1024];
    __shared__ float tmp[16];
#pragma unroll
    for (int i = 0; i < 4; ++i) {
        int h = tid + i * 256;
        float v = 0.f;
#pragma unroll
        for (int sc = 0; sc < 8; ++sc) v += ctxp[((size_t)sc * 64 + b) * 1024 + h];
        cl[h] = v;
    }
    __syncthreads();
    for (int e = wv; e < 10; e += 4) {
        const float* ev = events + e * 1024;
        float a = 0.f;
#pragma unroll
        for (int kk = 0; kk < 1024; kk += 64) a += cl[kk + lane] * ev[kk + lane];
#pragma unroll
        for (int off = 1; off < 64; off <<= 1) a += __shfl_xor(a, off);
        if (lane == 0) tmp[e] = a;
    }
    __syncthreads();
    if (tid < 10) {
        float s2 = 0.f;
#pragma unroll
        for (int e = 0; e < 10; ++e) s2 += Wg[tid * 10 + e] * tmp[e];
        out[OUT_SIM + b * 10 + tid] = s2;
    }
}

// ---------------------------------------------------------------------------
// k_castW: WcatB[r][k] = bf16( k<1035 ? Wih[r][k] : k<2059 ? Whh[r][k-1035] : 0 )
__global__ __launch_bounds__(256) void k_castW(const float* __restrict__ Wih,
                                               const float* __restrict__ Whh,
                                               unsigned short* __restrict__ WcatB) {
    unsigned int idx = blockIdx.x * 256 + threadIdx.x;   // 4096*2112
    unsigned int r = idx / KP;
    unsigned int k = idx - r * KP;
    float v = 0.f;
    if (k < 1035)      v = Wih[(size_t)r * 1035 + k];
    else if (k < 2059) v = Whh[(size_t)r * 1024 + (k - 1035)];
    WcatB[idx] = f2bf(v);
}

// k_xinB: xinB[b][k] = bf16 of [ctx(1024), sim(10), x(1), h0(1024), pad]
__global__ __launch_bounds__(256) void k_xinB(const float* __restrict__ ctxp,
                                              const float* __restrict__ simOut,
                                              const float* __restrict__ x,
                                              const float* __restrict__ h0,
                                              unsigned short* __restrict__ xinB) {
    unsigned int idx = blockIdx.x * 256 + threadIdx.x;   // 64*2112
    unsigned int b = idx / KP;
    unsigned int k = idx - b * KP;
    float v = 0.f;
    if (k < 1024) {
        v = 0.f;
#pragma unroll
        for (int sc = 0; sc < 8; ++sc) v += ctxp[((size_t)sc * 64 + b) * 1024 + k];
    }
    else if (k < 1034)  v = simOut[b * 10 + (k - 1024)];
    else if (k == 1034) v = x[b];
    else if (k < 2059)  v = h0[b * 1024 + (k - 1035)];
    xinB[idx] = f2bf(v);
}

// ---------------------------------------------------------------------------
// k5_gemm: G[64,4096] = xinB[64,KP] . WcatB[4096,KP]^T  with split-K 8.
__global__ __launch_bounds__(256) void k5_gemm(const unsigned short* __restrict__ xinB,
                                               const unsigned short* __restrict__ WcatB,
                                               float* __restrict__ gpart) {
    __shared__ short As[4096];
    __shared__ short Bs[8192];

    const int n0 = blockIdx.x * 128;
    const int sp = blockIdx.y;
    const int kbeg   = (sp == 0) ? 0 : (5 + (sp - 1) * 4) * 64;
    const int ksteps = (sp == 0) ? 5 : 4;
    const int tid  = threadIdx.x;
    const int wave = tid >> 6;
    const int lane = tid & 63;
    const int wr = wave >> 1;
    const int wc = wave & 1;
    const int q4 = lane >> 4;
    const int ml = lane & 15;

    f32x4 acc[2][4];
#pragma unroll
    for (int i = 0; i < 2; ++i)
#pragma unroll
        for (int j = 0; j < 4; ++j) acc[i][j] = (f32x4){0.f, 0.f, 0.f, 0.f};

    const unsigned short* bTile = WcatB + (size_t)n0 * KP;

    for (int kk = 0; kk < ksteps; ++kk) {
        int k0 = kbeg + kk * 64;
        __syncthreads();
#pragma unroll
        for (int t = 0; t < 2; ++t) {
            int q = wave * 2 + t;
            ASYNC_CP16(xinB + (size_t)lane * KP + k0 + q * 8, &As[(q * 64) * 8]);
        }
#pragma unroll
        for (int t = 0; t < 4; ++t) {
            int cb = t * 4 + wave;
            int q  = cb >> 1;
            int mb = (cb & 1) << 6;
            ASYNC_CP16(bTile + (size_t)(mb + lane) * KP + k0 + q * 8,
                       &Bs[(q * 128 + mb) * 8]);
        }
        __syncthreads();
#pragma unroll
        for (int s = 0; s < 2; ++s) {
            bf16x8 af[2], bfr[4];
#pragma unroll
            for (int i = 0; i < 2; ++i)
                af[i] = *(const bf16x8*)&As[((((s << 2) + q4) * 64) + wr * 32 + (i << 4) + ml) * 8];
#pragma unroll
            for (int j = 0; j < 4; ++j)
                bfr[j] = *(const bf16x8*)&Bs[((((s << 2) + q4) * 128) + wc * 64 + (j << 4) + ml) * 8];
#pragma unroll
            for (int i = 0; i < 2; ++i)
#pragma unroll
                for (int j = 0; j < 4; ++j)
                    acc[i][j] = __builtin_amdgcn_mfma_f32_16x16x32_bf16(af[i], bfr[j], acc[i][j], 0, 0, 0);
        }
    }
#pragma unroll
    for (int i = 0; i < 2; ++i)
#pragma unroll
        for (int j = 0; j < 4; ++j)
#pragma unroll
            for (int r = 0; r < 4; ++r) {
                int m = wr * 32 + (i << 4) + q4 * 4 + r;
                int n = n0 + wc * 64 + (j << 4) + ml;
                gpart[((size_t)sp * 64 + m) * 4096 + n] = acc[i][j][r];
            }
}

// k56: gates = sum_sp gpart + biases -> LSTM cell -> h,c; then fused LayerNorm+fin.
// One block per b; thread tid handles u = tid + 256*r, r=0..3.
__global__ __launch_bounds__(256) void k56_lstm_ln(const float* __restrict__ gpart,
                                                   const float* __restrict__ bih,
                                                   const float* __restrict__ bhh,
                                                   const float* __restrict__ c0,
                                                   const float* __restrict__ lng,
                                                   const float* __restrict__ lnb,
                                                   const float* __restrict__ Wfin,
                                                   const float* __restrict__ bfin,
                                                   float* __restrict__ out) {
    int b = blockIdx.x, tid = threadIdx.x;
    __shared__ float red[8];
    float hn[4];
#pragma unroll
    for (int r = 0; r < 4; ++r) {
        int u = tid + (r << 8);
        float g[4];
#pragma unroll
        for (int gt = 0; gt < 4; ++gt) {
            int rr = gt * 1024 + u;
            float a = bih[rr] + bhh[rr];
#pragma unroll
            for (int sp = 0; sp < 8; ++sp)
                a += gpart[((size_t)sp * 64 + b) * 4096 + rr];
            g[gt] = a;
        }
        float cp = c0[b * 1024 + u];
        float si = 1.f / (1.f + __expf(-g[0]));
        float sf = 1.f / (1.f + __expf(-g[1]));
        float so = 1.f / (1.f + __expf(-g[3]));
        float cn = sf * cp + si * tanhf(g[2]);
        hn[r] = so * tanhf(cn);
        out[OUT_H + b * 1024 + u] = hn[r];
        out[OUT_C + b * 1024 + u] = cn;
    }
    // LayerNorm + final dot
    float mu = block_sum256(hn[0] + hn[1] + hn[2] + hn[3], red, tid) * (1.f / 1024.f);
    float d0 = hn[0] - mu, d1 = hn[1] - mu, d2 = hn[2] - mu, d3 = hn[3] - mu;
    float var = block_sum256(d0 * d0 + d1 * d1 + d2 * d2 + d3 * d3, red, tid) * (1.f / 1024.f);
    float rstd = rsqrtf(var + 1e-5f);
    float acc = (d0 * rstd * lng[tid]       + lnb[tid])       * Wfin[tid]
              + (d1 * rstd * lng[tid + 256] + lnb[tid + 256]) * Wfin[tid + 256]
              + (d2 * rstd * lng[tid + 512] + lnb[tid + 512]) * Wfin[tid + 512]
              + (d3 * rstd * lng[tid + 768] + lnb[tid + 768]) * Wfin[tid + 768];
    acc = block_sum256(acc, red, tid);
    if (tid == 0) out[OUT_FIN + b] = acc + bfin[0];
}

// ---------------------------------------------------------------------------
extern "C" void kernel_launch(void* const* d_in, const int* in_sizes, int n_in,
                              void* d_out, int out_size, void* d_ws, size_t ws_size,
                              hipStream_t stream) {
    (void)in_sizes; (void)n_in; (void)out_size; (void)ws_size;
    const float* x    = (const float*)d_in[0];
    const float* h0   = (const float*)d_in[1];
    const float* c0   = (const float*)d_in[2];
    const float* enc  = (const float*)d_in[3];
    const float* Wenc = (const float*)d_in[4];
    const float* Wdec = (const float*)d_in[5];
    const float* wval = (const float*)d_in[6];
    const float* Wg   = (const float*)d_in[7];
    const float* ev   = (const float*)d_in[8];
    const float* Wih  = (const float*)d_in[9];
    const float* Whh  = (const float*)d_in[10];
    const float* bih  = (const float*)d_in[11];
    const float* bhh  = (const float*)d_in[12];
    const float* lng  = (const float*)d_in[13];
    const float* lnb  = (const float*)d_in[14];
    const float* Wfin = (const float*)d_in[15];
    const float* bfin = (const float*)d_in[16];

    float* out  = (float*)d_out;
    float* ws   = (float*)d_ws;
    unsigned short* encB  = (unsigned short*)(ws + WS_ENCB);
    unsigned short* wencB = (unsigned short*)(ws + WS_WENCB);
    unsigned short* wdecB = (unsigned short*)(ws + WS_WDECB);
    unsigned short* h0B   = (unsigned short*)(ws + WS_H0B);
    float* dpart = ws + WS_DPART;
    float* wts   = ws + WS_WTS;
    float* part  = ws + WS_PART;
    float* ctxp  = ws + WS_CTXP;                                // alias over part (dead after k3a)
    unsigned short* WcatB = (unsigned short*)(ws + WS_WCATB);   // alias encB (dead after k3b)
    float* gpart = ws + WS_GPART;                               // alias encB
    unsigned short* xinB  = (unsigned short*)(ws + WS_XINB);    // alias encB

    k_cast     <<<17440, 256, 0, stream>>>(enc, Wenc, Wdec, h0, encB, wencB, wdecB, h0B);
    k1_gemm    <<<dim3(8, 8), 256, 0, stream>>>(h0B, wdecB, dpart);
    k2_scores  <<<2048, 512, 0, stream>>>(encB, wencB, dpart, wval, part);
    k3a_softmax<<<64, 256, 0, stream>>>(part, wts, out);
    k3b_context<<<dim3(16, 64), 256, 0, stream>>>(encB, wts, ctxp);
    k4_sim     <<<64, 256, 0, stream>>>(ctxp, ev, Wg, out);
    // encB region dead past k3b -> safe for LSTM buffers
    k_castW    <<<33792, 256, 0, stream>>>(Wih, Whh, WcatB);
    k_xinB     <<<528, 256, 0, stream>>>(ctxp, out + OUT_SIM, x, h0, xinB);
    k5_gemm    <<<dim3(32, 8), 256, 0, stream>>>(xinB, WcatB, gpart);
    k56_lstm_ln<<<64, 256, 0, stream>>>(gpart, bih, bhh, c0, lng, lnb, Wfin, bfin, out);
}